// Round 1
// baseline (1838.247 us; speedup 1.0000x reference)
//
#include <hip/hip_runtime.h>
#include <hip/hip_bf16.h>

#define V 30000
#define D 300
#define H 4
#define C 300
#define HC 1200
#define B 2
#define T 800
#define E 1600          // real edges per sample (head->rel, rel->tail)
#define MAXM 2400       // max unique nodes per sample (3*T)
#define NEG 0.2f
#define SCAN_CH ((MAXM + 255) / 256)

// ---------------- graph build ----------------

__global__ void k_init(int* map, int* list, int* deg, int* fill, int* mcnt) {
    int i = blockIdx.x * blockDim.x + threadIdx.x;
    if (i < B * V) map[i] = -1;
    if (i < B * MAXM) { list[i] = 0; deg[i] = 0; fill[i] = 0; }
    if (i < B) mcnt[i] = 0;
}

__global__ void k_mark(const int* __restrict__ kg, int* map) {
    int i = blockIdx.x * blockDim.x + threadIdx.x;
    if (i >= B * T * 3) return;
    int b = i / (T * 3);
    map[b * V + kg[i]] = 1;   // benign duplicate stores
}

__global__ void k_compact(int* map, int* list, int* mcnt) {
    int i = blockIdx.x * blockDim.x + threadIdx.x;
    if (i >= B * V) return;
    int b = i / V;
    if (map[i] == 1) {
        int idx = atomicAdd(&mcnt[b], 1);
        map[i] = idx;
        list[b * MAXM + idx] = i - b * V;
    }
}

__global__ void k_edges(const int* __restrict__ kg, const int* __restrict__ map,
                        int* esrc, int* edst, int* deg, int* tric) {
    int i = blockIdx.x * blockDim.x + threadIdx.x;
    if (i >= B * T) return;
    int b = i / T, t = i % T;
    const int* kk = kg + ((long)b * T + t) * 3;
    int hc = map[b * V + kk[0]];
    int rc = map[b * V + kk[1]];
    int tc = map[b * V + kk[2]];
    int eb = b * E;
    esrc[eb + t]     = hc;  edst[eb + t]     = rc;   // head -> rel
    esrc[eb + T + t] = rc;  edst[eb + T + t] = tc;   // rel  -> tail
    atomicAdd(&deg[b * MAXM + rc], 1);
    atomicAdd(&deg[b * MAXM + tc], 1);
    int* tr = tric + ((long)b * T + t) * 3;
    tr[0] = hc; tr[1] = rc; tr[2] = tc;
}

__global__ void k_scan(const int* __restrict__ deg, int* __restrict__ off) {
    int b = blockIdx.x;
    deg += b * MAXM; off += b * (MAXM + 1);
    __shared__ int ts[256];
    int t = threadIdx.x;
    int base = t * SCAN_CH;
    int loc[SCAN_CH];
    int sum = 0;
#pragma unroll
    for (int j = 0; j < SCAN_CH; ++j) {
        int v = (base + j < MAXM) ? deg[base + j] : 0;
        sum += v; loc[j] = sum;
    }
    ts[t] = sum; __syncthreads();
    for (int s = 1; s < 256; s <<= 1) {
        int v = (t >= s) ? ts[t - s] : 0;
        __syncthreads();
        ts[t] += v;
        __syncthreads();
    }
    int excl = (t > 0) ? ts[t - 1] : 0;
#pragma unroll
    for (int j = 0; j < SCAN_CH; ++j)
        if (base + j < MAXM) off[base + j + 1] = excl + loc[j];
    if (t == 0) off[0] = 0;
}

__global__ void k_scatter(const int* __restrict__ esrc, const int* __restrict__ edst,
                          const int* __restrict__ off, int* fill, int* csr) {
    int i = blockIdx.x * blockDim.x + threadIdx.x;
    if (i >= B * E) return;
    int b = i / E;
    int d = edst[i];
    int pos = off[b * (MAXM + 1) + d] + atomicAdd(&fill[b * MAXM + d], 1);
    csr[b * E + pos] = esrc[i];
}

// ---------------- generic tiled f32 GEMM: Y = gather(X) @ W + bias ----------------
// X: [.., K] rows gathered via rows[] (or identity); W: [K, N]; Y: [M, N]
__global__ __launch_bounds__(256) void k_gemm(
    const float* __restrict__ X, long sX,
    const int* __restrict__ rows,
    const float* __restrict__ W,
    const float* __restrict__ bias,
    float* __restrict__ Y, long sY,
    int M, int K, int N) {
    int b = blockIdx.z;
    X += (long)b * sX;
    Y += (long)b * sY;
    const int* rw = rows ? rows + (long)b * MAXM : nullptr;
    __shared__ float As[16][68];   // [k][m], pitch 68 -> 16B-aligned float4 reads
    __shared__ float Bs[16][68];   // [k][n]
    int m0 = blockIdx.y * 64, n0 = blockIdx.x * 64;
    int tid = threadIdx.x;
    int tm = (tid >> 4) << 2, tn = (tid & 15) << 2;
    float acc[4][4] = {};
    for (int k0 = 0; k0 < K; k0 += 16) {
        int ka = tid & 15, ra = tid >> 4;
#pragma unroll
        for (int p = 0; p < 4; ++p) {
            int row = ra + p * 16;
            int gm = m0 + row, gk = k0 + ka;
            float v = 0.f;
            if (gm < M && gk < K) {
                int src = rw ? rw[gm] : gm;
                v = X[(long)src * K + gk];
            }
            As[ka][row] = v;
        }
        int nb = tid & 63, kb = tid >> 6;
#pragma unroll
        for (int p = 0; p < 4; ++p) {
            int kk2 = kb + p * 4;
            int gk = k0 + kk2, gn = n0 + nb;
            Bs[kk2][nb] = (gk < K && gn < N) ? W[(long)gk * N + gn] : 0.f;
        }
        __syncthreads();
#pragma unroll
        for (int kk = 0; kk < 16; ++kk) {
            float4 a4 = *(const float4*)&As[kk][tm];
            float4 b4 = *(const float4*)&Bs[kk][tn];
            float a[4] = {a4.x, a4.y, a4.z, a4.w};
            float bb[4] = {b4.x, b4.y, b4.z, b4.w};
#pragma unroll
            for (int i2 = 0; i2 < 4; ++i2)
#pragma unroll
                for (int j = 0; j < 4; ++j)
                    acc[i2][j] += a[i2] * bb[j];
        }
        __syncthreads();
    }
#pragma unroll
    for (int i2 = 0; i2 < 4; ++i2) {
        int gm = m0 + tm + i2;
        if (gm >= M) continue;
#pragma unroll
        for (int j = 0; j < 4; ++j) {
            int gn = n0 + tn + j;
            if (gn >= N) continue;
            Y[(long)gm * N + gn] = acc[i2][j] + bias[gn];
        }
    }
}

// ---------------- GATv2 attention + aggregate + bias + relu ----------------
// one block per node, one wave per head
__global__ __launch_bounds__(256) void k_att(
    const float* __restrict__ XL, const float* __restrict__ XR, long sX,
    const int* __restrict__ deg, const int* __restrict__ off, const int* __restrict__ csr,
    const float* __restrict__ att, const float* __restrict__ bias,
    float* __restrict__ OUT, long sO) {
    int b = blockIdx.y;
    int i = blockIdx.x;
    const float* xl = XL + (long)b * sX;
    const float* xr = XR + (long)b * sX;
    float* out = OUT + (long)b * sO;
    int lane = threadIdx.x & 63;
    int h = threadIdx.x >> 6;

    float xr_reg[5], att_reg[5];
#pragma unroll
    for (int q = 0; q < 5; ++q) {
        int c = lane + q * 64;
        if (c < C) {
            xr_reg[q] = xr[(long)i * HC + h * C + c];
            att_reg[q] = att[h * C + c];
        } else { xr_reg[q] = 0.f; att_reg[q] = 0.f; }
    }
    int dg = deg[b * MAXM + i];
    int o0 = off[b * (MAXM + 1) + i];
    const int* cs = csr + b * E;

    auto logit = [&](int s) -> float {
        const float* xls = xl + (long)s * HC + h * C;
        float part = 0.f;
#pragma unroll
        for (int q = 0; q < 5; ++q) {
            int c = lane + q * 64;
            if (c < C) {
                float v = xls[c] + xr_reg[q];
                v = v > 0.f ? v : NEG * v;
                part += att_reg[q] * v;
            }
        }
#pragma unroll
        for (int m = 1; m < 64; m <<= 1) part += __shfl_xor(part, m);
        return part;
    };

    // pass A: max over {self} + in-edges
    float mx = logit(i);
    for (int e = 0; e < dg; ++e) mx = fmaxf(mx, logit(cs[o0 + e]));

    // pass B: exp-sum + weighted accumulation
    float den = 0.f;
    float acc[5] = {0.f, 0.f, 0.f, 0.f, 0.f};
    auto accum = [&](int s) {
        const float* xls = xl + (long)s * HC + h * C;
        float part = 0.f;
        float xlv[5];
#pragma unroll
        for (int q = 0; q < 5; ++q) {
            int c = lane + q * 64;
            if (c < C) {
                float xv = xls[c];
                xlv[q] = xv;
                float v = xv + xr_reg[q];
                v = v > 0.f ? v : NEG * v;
                part += att_reg[q] * v;
            } else xlv[q] = 0.f;
        }
#pragma unroll
        for (int m = 1; m < 64; m <<= 1) part += __shfl_xor(part, m);
        float p = expf(part - mx);
        den += p;
#pragma unroll
        for (int q = 0; q < 5; ++q) acc[q] += p * xlv[q];
    };
    accum(i);
    for (int e = 0; e < dg; ++e) accum(cs[o0 + e]);

    float inv = 1.f / den;
#pragma unroll
    for (int q = 0; q < 5; ++q) {
        int c = lane + q * 64;
        if (c < C) {
            float v = acc[q] * inv + bias[h * C + c];
            out[(long)i * HC + h * C + c] = v > 0.f ? v : 0.f;   // relu after each layer
        }
    }
}

// ---------------- final: out[b] = concat(w[head],w[rel],w[tail]) @ Wlii ----------------
__global__ __launch_bounds__(256) void k_final(
    const float* __restrict__ wb, long sW,
    const int* __restrict__ tric,
    const float* __restrict__ Wlii,
    float* __restrict__ out) {
    int b = blockIdx.z;
    const float* w = wb + (long)b * sW;
    const int* tr = tric + (long)b * T * 3;
    float* o = out + (long)b * T * 768;
    __shared__ float As[16][68];
    __shared__ float Bs[16][68];
    int m0 = blockIdx.y * 64, n0 = blockIdx.x * 64;
    int tid = threadIdx.x;
    int tm = (tid >> 4) << 2, tn = (tid & 15) << 2;
    float acc[4][4] = {};
    for (int k0 = 0; k0 < 900; k0 += 16) {
        int ka = tid & 15, ra = tid >> 4;
#pragma unroll
        for (int p = 0; p < 4; ++p) {
            int row = ra + p * 16;
            int gm = m0 + row, gk = k0 + ka;
            float v = 0.f;
            if (gm < T && gk < 900) {
                int part = gk / 300, kc = gk - part * 300;
                int src = tr[gm * 3 + part];
                v = w[(long)src * 300 + kc];
            }
            As[ka][row] = v;
        }
        int nb = tid & 63, kb = tid >> 6;
#pragma unroll
        for (int p = 0; p < 4; ++p) {
            int kk2 = kb + p * 4;
            int gk = k0 + kk2, gn = n0 + nb;
            Bs[kk2][nb] = (gk < 900 && gn < 768) ? Wlii[(long)gk * 768 + gn] : 0.f;
        }
        __syncthreads();
#pragma unroll
        for (int kk = 0; kk < 16; ++kk) {
            float4 a4 = *(const float4*)&As[kk][tm];
            float4 b4 = *(const float4*)&Bs[kk][tn];
            float a[4] = {a4.x, a4.y, a4.z, a4.w};
            float bb[4] = {b4.x, b4.y, b4.z, b4.w};
#pragma unroll
            for (int i2 = 0; i2 < 4; ++i2)
#pragma unroll
                for (int j = 0; j < 4; ++j)
                    acc[i2][j] += a[i2] * bb[j];
        }
        __syncthreads();
    }
#pragma unroll
    for (int i2 = 0; i2 < 4; ++i2) {
        int gm = m0 + tm + i2;
        if (gm >= T) continue;
#pragma unroll
        for (int j = 0; j < 4; ++j) {
            int gn = n0 + tn + j;
            o[(long)gm * 768 + gn] = acc[i2][j];
        }
    }
}

extern "C" void kernel_launch(void* const* d_in, const int* in_sizes, int n_in,
                              void* d_out, int out_size, void* d_ws, size_t ws_size,
                              hipStream_t stream) {
    const int*   kg    = (const int*)d_in[0];
    const float* emb   = (const float*)d_in[1];
    const float* Wl1   = (const float*)d_in[2];
    const float* bl1   = (const float*)d_in[3];
    const float* Wr1   = (const float*)d_in[4];
    const float* br1   = (const float*)d_in[5];
    const float* att1  = (const float*)d_in[6];
    const float* bias1 = (const float*)d_in[7];
    const float* Wl2   = (const float*)d_in[8];
    const float* bl2   = (const float*)d_in[9];
    const float* Wr2   = (const float*)d_in[10];
    const float* br2   = (const float*)d_in[11];
    const float* att2  = (const float*)d_in[12];
    const float* bias2 = (const float*)d_in[13];
    const float* Wp1   = (const float*)d_in[14];
    const float* bp1   = (const float*)d_in[15];
    const float* Wp2   = (const float*)d_in[16];
    const float* bp2   = (const float*)d_in[17];
    const float* Wlii  = (const float*)d_in[18];
    float* out = (float*)d_out;

    char* ws = (char*)d_ws;
    size_t o = 0;
    auto alloc = [&](size_t bytes) -> void* {
        void* p = ws + o;
        o = (o + bytes + 255) & ~(size_t)255;
        return p;
    };
    int* map  = (int*)alloc(sizeof(int) * B * V);
    int* list = (int*)alloc(sizeof(int) * B * MAXM);
    int* mcnt = (int*)alloc(sizeof(int) * B);
    int* deg  = (int*)alloc(sizeof(int) * B * MAXM);
    int* off  = (int*)alloc(sizeof(int) * B * (MAXM + 1));
    int* fill = (int*)alloc(sizeof(int) * B * MAXM);
    int* esrc = (int*)alloc(sizeof(int) * B * E);
    int* edst = (int*)alloc(sizeof(int) * B * E);
    int* csr  = (int*)alloc(sizeof(int) * B * E);
    int* tric = (int*)alloc(sizeof(int) * B * T * 3);
    float* Abuf = (float*)alloc(sizeof(float) * (size_t)B * MAXM * HC);
    float* Bbuf = (float*)alloc(sizeof(float) * (size_t)B * MAXM * HC);
    float* Hbuf = (float*)alloc(sizeof(float) * (size_t)B * MAXM * HC);
    (void)ws_size;

    long sN = (long)MAXM * HC;

    k_init<<<(B * V + 255) / 256, 256, 0, stream>>>(map, list, deg, fill, mcnt);
    k_mark<<<(B * T * 3 + 255) / 256, 256, 0, stream>>>(kg, map);
    k_compact<<<(B * V + 255) / 256, 256, 0, stream>>>(map, list, mcnt);
    k_edges<<<(B * T + 255) / 256, 256, 0, stream>>>(kg, map, esrc, edst, deg, tric);
    k_scan<<<B, 256, 0, stream>>>(deg, off);
    k_scatter<<<(B * E + 255) / 256, 256, 0, stream>>>(esrc, edst, off, fill, csr);

    dim3 g1((HC + 63) / 64, (MAXM + 63) / 64, B);
    // layer 1: gather embeddings
    k_gemm<<<g1, 256, 0, stream>>>(emb, 0, list, Wl1, bl1, Abuf, sN, MAXM, D, HC);
    k_gemm<<<g1, 256, 0, stream>>>(emb, 0, list, Wr1, br1, Bbuf, sN, MAXM, D, HC);
    dim3 ga(MAXM, B);
    k_att<<<ga, 256, 0, stream>>>(Abuf, Bbuf, sN, deg, off, csr, att1, bias1, Hbuf, sN);
    // layer 2
    k_gemm<<<g1, 256, 0, stream>>>(Hbuf, sN, nullptr, Wl2, bl2, Abuf, sN, MAXM, HC, HC);
    k_gemm<<<g1, 256, 0, stream>>>(Hbuf, sN, nullptr, Wr2, br2, Bbuf, sN, MAXM, HC, HC);
    k_att<<<ga, 256, 0, stream>>>(Abuf, Bbuf, sN, deg, off, csr, att2, bias2, Hbuf, sN);
    // projections: t1 = H @ Wp1 + bp1 (into Abuf), w = t1 @ Wp2 + bp2 (into Bbuf)
    dim3 g2((C + 63) / 64, (MAXM + 63) / 64, B);
    k_gemm<<<g2, 256, 0, stream>>>(Hbuf, sN, nullptr, Wp1, bp1, Abuf, sN, MAXM, HC, C);
    k_gemm<<<g2, 256, 0, stream>>>(Abuf, sN, nullptr, Wp2, bp2, Bbuf, sN, MAXM, C, C);
    // final
    dim3 g3(768 / 64, (T + 63) / 64, B);
    k_final<<<g3, 256, 0, stream>>>(Bbuf, sN, tric, Wlii, out);
}

// Round 2
// 489.081 us; speedup vs baseline: 3.7586x; 3.7586x over previous
//
#include <hip/hip_runtime.h>
#include <hip/hip_bf16.h>

#define V 30000
#define D 300
#define H 4
#define C 300
#define HC 1200
#define B 2
#define T 800
#define E 1600          // real edges per sample
#define MAXM 2400       // max unique nodes per sample
#define NEG 0.2f
#define SCAN_CH ((MAXM + 255) / 256)

#define MR 2432         // node rows padded to 128-multiple (19*128)
#define KD 320          // D padded to 32-multiple
#define KHC 1216        // HC padded to 32-multiple
#define WB_LD 304       // w bf16 leading dim (300 -> 304, 8-mult)
#define KF 928          // 900 padded
#define FRW 896         // T rows padded (7*128)

typedef __attribute__((ext_vector_type(8))) unsigned short u16x8;
typedef __attribute__((ext_vector_type(8))) short s16x8;
typedef __attribute__((ext_vector_type(4))) float f32x4;

__device__ inline unsigned short f2b(float v) {
    unsigned u = __float_as_uint(v);
    unsigned r = (u + 0x7FFFu + ((u >> 16) & 1u)) >> 16;
    return (unsigned short)r;
}
__device__ inline float b2f(unsigned short u) {
    return __uint_as_float(((unsigned)u) << 16);
}

// ---------------- graph build ----------------

__global__ void k_init(int* map, int* list, int* deg, int* fill, int* mcnt) {
    int i = blockIdx.x * blockDim.x + threadIdx.x;
    if (i < B * V) map[i] = -1;
    if (i < B * MAXM) { list[i] = 0; deg[i] = 0; fill[i] = 0; }
    if (i < B) mcnt[i] = 0;
}

__global__ void k_mark(const int* __restrict__ kg, int* map) {
    int i = blockIdx.x * blockDim.x + threadIdx.x;
    if (i >= B * T * 3) return;
    int b = i / (T * 3);
    map[b * V + kg[i]] = 1;
}

__global__ void k_compact(int* map, int* list, int* mcnt) {
    int i = blockIdx.x * blockDim.x + threadIdx.x;
    if (i >= B * V) return;
    int b = i / V;
    if (map[i] == 1) {
        int idx = atomicAdd(&mcnt[b], 1);
        map[i] = idx;
        list[b * MAXM + idx] = i - b * V;
    }
}

__global__ void k_edges(const int* __restrict__ kg, const int* __restrict__ map,
                        int* esrc, int* edst, int* deg, int* tric) {
    int i = blockIdx.x * blockDim.x + threadIdx.x;
    if (i >= B * T) return;
    int b = i / T, t = i % T;
    const int* kk = kg + ((long)b * T + t) * 3;
    int hc = map[b * V + kk[0]];
    int rc = map[b * V + kk[1]];
    int tc = map[b * V + kk[2]];
    int eb = b * E;
    esrc[eb + t]     = hc;  edst[eb + t]     = rc;
    esrc[eb + T + t] = rc;  edst[eb + T + t] = tc;
    atomicAdd(&deg[b * MAXM + rc], 1);
    atomicAdd(&deg[b * MAXM + tc], 1);
    int* tr = tric + ((long)b * T + t) * 3;
    tr[0] = hc; tr[1] = rc; tr[2] = tc;
}

__global__ void k_scan(const int* __restrict__ deg, int* __restrict__ off) {
    int b = blockIdx.x;
    deg += b * MAXM; off += b * (MAXM + 1);
    __shared__ int ts[256];
    int t = threadIdx.x;
    int base = t * SCAN_CH;
    int loc[SCAN_CH];
    int sum = 0;
#pragma unroll
    for (int j = 0; j < SCAN_CH; ++j) {
        int v = (base + j < MAXM) ? deg[base + j] : 0;
        sum += v; loc[j] = sum;
    }
    ts[t] = sum; __syncthreads();
    for (int s = 1; s < 256; s <<= 1) {
        int v = (t >= s) ? ts[t - s] : 0;
        __syncthreads();
        ts[t] += v;
        __syncthreads();
    }
    int excl = (t > 0) ? ts[t - 1] : 0;
#pragma unroll
    for (int j = 0; j < SCAN_CH; ++j)
        if (base + j < MAXM) off[base + j + 1] = excl + loc[j];
    if (t == 0) off[0] = 0;
}

__global__ void k_scatter(const int* __restrict__ esrc, const int* __restrict__ edst,
                          const int* __restrict__ off, int* fill, int* csr) {
    int i = blockIdx.x * blockDim.x + threadIdx.x;
    if (i >= B * E) return;
    int b = i / E;
    int d = edst[i];
    int pos = off[b * (MAXM + 1) + d] + atomicAdd(&fill[b * MAXM + d], 1);
    csr[b * E + pos] = esrc[i];
}

// ---------------- weight transpose f32 [K][N] -> bf16 [Np][Kp] ----------------
__global__ void k_wt(const float* __restrict__ W, unsigned short* __restrict__ Wt,
                     int K, int N, int Kp) {
    __shared__ float t[32][33];
    int k0 = blockIdx.x * 32, n0 = blockIdx.y * 32;
    int tx = threadIdx.x, ty = threadIdx.y;
#pragma unroll
    for (int p = 0; p < 4; ++p) {
        int k = k0 + ty + p * 8, n = n0 + tx;
        t[ty + p * 8][tx] = (k < K && n < N) ? W[(long)k * N + n] : 0.f;
    }
    __syncthreads();
#pragma unroll
    for (int p = 0; p < 4; ++p) {
        int n = n0 + ty + p * 8, k = k0 + tx;
        Wt[(long)n * Kp + k] = f2b(t[tx][ty + p * 8]);
    }
}

// ---------------- embedding gather f32 -> bf16 padded ----------------
__global__ void k_embgather(const float* __restrict__ emb, const int* __restrict__ list,
                            unsigned short* __restrict__ Eb) {
    int b = blockIdx.y, i = blockIdx.x;
    int src = list[b * MAXM + i];
    const float* e = emb + (long)src * D;
    unsigned short* o = Eb + ((long)b * MR + i) * KD;
    for (int c = threadIdx.x; c < KD; c += 256)
        o[c] = (c < D) ? f2b(e[c]) : 0;
}

// ---------------- bf16 MFMA GEMM ----------------
// A bf16 [*][lda] (per-sample stride sA), Wt bf16 [Np][ldw] (row n = col of W),
// out = A @ W + bias -> optional f32 [ldf] and/or bf16 [ldb_] (zero-fill N..ldb_)
__global__ __launch_bounds__(256) void k_mgemm(
    const unsigned short* __restrict__ A, long sA, int lda,
    const unsigned short* __restrict__ Wt, int ldw,
    const float* __restrict__ bias,
    int M, int N, int K,
    float* __restrict__ outF, long sF, int ldf,
    unsigned short* __restrict__ outB, long sB, int ldb_) {
    int b = blockIdx.z;
    A += (long)b * sA;
    __shared__ unsigned short As[128][40];   // pitch 40 elems (80 B): 16B-aligned, phase-conflict-free b128
    __shared__ unsigned short Bs[128][40];
    int tid = threadIdx.x;
    int m0 = blockIdx.y * 128, n0 = blockIdx.x * 128;
    int w = tid >> 6, lane = tid & 63;
    int wr = (w >> 1) * 64, wc = (w & 1) * 64;
    int fr = lane & 15, fq = lane >> 4;
    int r0 = tid >> 2, sg = tid & 3;
    const unsigned short* Ap  = A  + (long)(m0 + r0) * lda + sg * 8;
    const unsigned short* Ap2 = A  + (long)(m0 + r0 + 64) * lda + sg * 8;
    const unsigned short* Bp  = Wt + (long)(n0 + r0) * ldw + sg * 8;
    const unsigned short* Bp2 = Wt + (long)(n0 + r0 + 64) * ldw + sg * 8;
    f32x4 acc[4][4] = {};
    for (int k0 = 0; k0 < K; k0 += 32) {
        *(u16x8*)&As[r0][sg * 8]      = *(const u16x8*)(Ap + k0);
        *(u16x8*)&As[r0 + 64][sg * 8] = *(const u16x8*)(Ap2 + k0);
        *(u16x8*)&Bs[r0][sg * 8]      = *(const u16x8*)(Bp + k0);
        *(u16x8*)&Bs[r0 + 64][sg * 8] = *(const u16x8*)(Bp2 + k0);
        __syncthreads();
        s16x8 af[4], bfr[4];
#pragma unroll
        for (int m = 0; m < 4; ++m)
            af[m] = *(const s16x8*)&As[wr + m * 16 + fr][fq * 8];
#pragma unroll
        for (int n = 0; n < 4; ++n)
            bfr[n] = *(const s16x8*)&Bs[wc + n * 16 + fr][fq * 8];
#pragma unroll
        for (int m = 0; m < 4; ++m)
#pragma unroll
            for (int n = 0; n < 4; ++n)
                acc[m][n] = __builtin_amdgcn_mfma_f32_16x16x32_bf16(af[m], bfr[n], acc[m][n], 0, 0, 0);
        __syncthreads();
    }
    float* oF = outF ? outF + (long)b * sF : nullptr;
    unsigned short* oB = outB ? outB + (long)b * sB : nullptr;
#pragma unroll
    for (int m = 0; m < 4; ++m) {
        int rb = m0 + wr + m * 16 + fq * 4;
#pragma unroll
        for (int n = 0; n < 4; ++n) {
            int col = n0 + wc + n * 16 + fr;
#pragma unroll
            for (int j = 0; j < 4; ++j) {
                int row = rb + j;
                if (row >= M) continue;
                if (col < N) {
                    float v = acc[m][n][j] + (bias ? bias[col] : 0.f);
                    if (oF) oF[(long)row * ldf + col] = v;
                    if (oB) oB[(long)row * ldb_ + col] = f2b(v);
                } else if (oB && col < ldb_) {
                    oB[(long)row * ldb_ + col] = 0;
                }
            }
        }
    }
}

// ---------------- GATv2 attention (bf16 IO, f32 math) ----------------
__global__ __launch_bounds__(256) void k_att(
    const unsigned short* __restrict__ XL, const unsigned short* __restrict__ XR,
    const int* __restrict__ deg, const int* __restrict__ off, const int* __restrict__ csr,
    const float* __restrict__ att, const float* __restrict__ bias,
    unsigned short* __restrict__ OUT) {
    long sX = (long)MR * KHC;
    int b = blockIdx.y;
    int i = blockIdx.x;
    const unsigned short* xl = XL + (long)b * sX;
    const unsigned short* xr = XR + (long)b * sX;
    unsigned short* out = OUT + (long)b * sX;
    int lane = threadIdx.x & 63;
    int h = threadIdx.x >> 6;

    float xr_reg[5], att_reg[5];
#pragma unroll
    for (int q = 0; q < 5; ++q) {
        int c = lane + q * 64;
        if (c < C) {
            xr_reg[q] = b2f(xr[(long)i * KHC + h * C + c]);
            att_reg[q] = att[h * C + c];
        } else { xr_reg[q] = 0.f; att_reg[q] = 0.f; }
    }
    int dg = deg[b * MAXM + i];
    int o0 = off[b * (MAXM + 1) + i];
    const int* cs = csr + b * E;

    auto logit = [&](int s) -> float {
        const unsigned short* xls = xl + (long)s * KHC + h * C;
        float part = 0.f;
#pragma unroll
        for (int q = 0; q < 5; ++q) {
            int c = lane + q * 64;
            if (c < C) {
                float v = b2f(xls[c]) + xr_reg[q];
                v = v > 0.f ? v : NEG * v;
                part += att_reg[q] * v;
            }
        }
#pragma unroll
        for (int m = 1; m < 64; m <<= 1) part += __shfl_xor(part, m);
        return part;
    };

    float mx = logit(i);
    for (int e = 0; e < dg; ++e) mx = fmaxf(mx, logit(cs[o0 + e]));

    float den = 0.f;
    float acc[5] = {0.f, 0.f, 0.f, 0.f, 0.f};
    auto accum = [&](int s) {
        const unsigned short* xls = xl + (long)s * KHC + h * C;
        float part = 0.f;
        float xlv[5];
#pragma unroll
        for (int q = 0; q < 5; ++q) {
            int c = lane + q * 64;
            if (c < C) {
                float xv = b2f(xls[c]);
                xlv[q] = xv;
                float v = xv + xr_reg[q];
                v = v > 0.f ? v : NEG * v;
                part += att_reg[q] * v;
            } else xlv[q] = 0.f;
        }
#pragma unroll
        for (int m = 1; m < 64; m <<= 1) part += __shfl_xor(part, m);
        float p = expf(part - mx);
        den += p;
#pragma unroll
        for (int q = 0; q < 5; ++q) acc[q] += p * xlv[q];
    };
    accum(i);
    for (int e = 0; e < dg; ++e) accum(cs[o0 + e]);

    float inv = 1.f / den;
#pragma unroll
    for (int q = 0; q < 5; ++q) {
        int c = lane + q * 64;
        if (c < C) {
            float v = acc[q] * inv + bias[h * C + c];
            out[(long)i * KHC + h * C + c] = f2b(v > 0.f ? v : 0.f);
        }
    }
    if (h == 0 && lane < KHC - HC)
        out[(long)i * KHC + HC + lane] = 0;   // zero K-pad cols
}

// ---------------- final A gather: concat(w[h],w[r],w[t]) bf16 padded ----------------
__global__ void k_fgather(const unsigned short* __restrict__ wb, const int* __restrict__ tric,
                          unsigned short* __restrict__ Af) {
    int b = blockIdx.y, t = blockIdx.x;
    const int* tr = tric + ((long)b * T + t) * 3;
    const unsigned short* w = wb + (long)b * (long)MR * WB_LD;
    unsigned short* o = Af + ((long)b * FRW + t) * KF;
    for (int c = threadIdx.x; c < KF; c += 256) {
        if (c < 900) {
            int part = c / 300, kc = c - part * 300;
            o[c] = w[(long)tr[part] * WB_LD + kc];
        } else o[c] = 0;
    }
}

extern "C" void kernel_launch(void* const* d_in, const int* in_sizes, int n_in,
                              void* d_out, int out_size, void* d_ws, size_t ws_size,
                              hipStream_t stream) {
    const int*   kg    = (const int*)d_in[0];
    const float* emb   = (const float*)d_in[1];
    const float* Wl1   = (const float*)d_in[2];
    const float* bl1   = (const float*)d_in[3];
    const float* Wr1   = (const float*)d_in[4];
    const float* br1   = (const float*)d_in[5];
    const float* att1  = (const float*)d_in[6];
    const float* bias1 = (const float*)d_in[7];
    const float* Wl2   = (const float*)d_in[8];
    const float* bl2   = (const float*)d_in[9];
    const float* Wr2   = (const float*)d_in[10];
    const float* br2   = (const float*)d_in[11];
    const float* att2  = (const float*)d_in[12];
    const float* bias2 = (const float*)d_in[13];
    const float* Wp1   = (const float*)d_in[14];
    const float* bp1   = (const float*)d_in[15];
    const float* Wp2   = (const float*)d_in[16];
    const float* bp2   = (const float*)d_in[17];
    const float* Wlii  = (const float*)d_in[18];
    float* out = (float*)d_out;

    char* ws = (char*)d_ws;
    size_t o = 0;
    auto alloc = [&](size_t bytes) -> void* {
        void* p = ws + o;
        o = (o + bytes + 255) & ~(size_t)255;
        return p;
    };
    int* map  = (int*)alloc(sizeof(int) * B * V);
    int* list = (int*)alloc(sizeof(int) * B * MAXM);
    int* mcnt = (int*)alloc(sizeof(int) * B);
    int* deg  = (int*)alloc(sizeof(int) * B * MAXM);
    int* off  = (int*)alloc(sizeof(int) * B * (MAXM + 1));
    int* fill = (int*)alloc(sizeof(int) * B * MAXM);
    int* esrc = (int*)alloc(sizeof(int) * B * E);
    int* edst = (int*)alloc(sizeof(int) * B * E);
    int* csr  = (int*)alloc(sizeof(int) * B * E);
    int* tric = (int*)alloc(sizeof(int) * B * T * 3);

    long sXb = (long)MR * KHC;                                        // bf16 act stride
    unsigned short* Xl = (unsigned short*)alloc(2LL * B * sXb);       // also aliased as Af
    unsigned short* Xr = (unsigned short*)alloc(2LL * B * sXb);
    unsigned short* Hb = (unsigned short*)alloc(2LL * B * sXb);       // also aliased as wb
    unsigned short* Eb = (unsigned short*)alloc(2LL * B * MR * KD);   // also aliased as T1b

    unsigned short* Wl1t = (unsigned short*)alloc(2LL * 1280 * KD);
    unsigned short* Wr1t = (unsigned short*)alloc(2LL * 1280 * KD);
    unsigned short* Wl2t = (unsigned short*)alloc(2LL * 1280 * KHC);
    unsigned short* Wr2t = (unsigned short*)alloc(2LL * 1280 * KHC);
    unsigned short* Wp1t = (unsigned short*)alloc(2LL * 384 * KHC);
    unsigned short* Wp2t = (unsigned short*)alloc(2LL * 384 * KD);
    unsigned short* Wft  = (unsigned short*)alloc(2LL * 768 * KF);
    (void)ws_size; (void)in_sizes; (void)n_in; (void)out_size;

    unsigned short* T1b = Eb;    // [B][MR][KD]  (Eb dead after layer-1 GEMMs)
    unsigned short* wb  = Hb;    // [B][MR][WB_LD] (Hb dead after Wp1)
    unsigned short* Af  = Xl;    // [B][FRW][KF]  (Xl dead after att2)

    // graph
    k_init<<<(B * V + 255) / 256, 256, 0, stream>>>(map, list, deg, fill, mcnt);
    k_mark<<<(B * T * 3 + 255) / 256, 256, 0, stream>>>(kg, map);
    k_compact<<<(B * V + 255) / 256, 256, 0, stream>>>(map, list, mcnt);
    k_edges<<<(B * T + 255) / 256, 256, 0, stream>>>(kg, map, esrc, edst, deg, tric);
    k_scan<<<B, 256, 0, stream>>>(deg, off);
    k_scatter<<<(B * E + 255) / 256, 256, 0, stream>>>(esrc, edst, off, fill, csr);

    // weights -> bf16 transposed
    dim3 wtb(32, 8);
    k_wt<<<dim3(KD / 32, 1280 / 32), wtb, 0, stream>>>(Wl1, Wl1t, D, HC, KD);
    k_wt<<<dim3(KD / 32, 1280 / 32), wtb, 0, stream>>>(Wr1, Wr1t, D, HC, KD);
    k_wt<<<dim3(KHC / 32, 1280 / 32), wtb, 0, stream>>>(Wl2, Wl2t, HC, HC, KHC);
    k_wt<<<dim3(KHC / 32, 1280 / 32), wtb, 0, stream>>>(Wr2, Wr2t, HC, HC, KHC);
    k_wt<<<dim3(KHC / 32, 384 / 32), wtb, 0, stream>>>(Wp1, Wp1t, HC, C, KHC);
    k_wt<<<dim3(KD / 32, 384 / 32), wtb, 0, stream>>>(Wp2, Wp2t, C, C, KD);
    k_wt<<<dim3(KF / 32, 768 / 32), wtb, 0, stream>>>(Wlii, Wft, 900, 768, KF);

    // embedding gather
    k_embgather<<<dim3(MAXM, B), 256, 0, stream>>>(emb, list, Eb);

    long sEb = (long)MR * KD;
    long sWb = (long)MR * WB_LD;
    long sAf = (long)FRW * KF;

    dim3 gL(10, 19, B);   // N=1200 -> 10, M=2400 -> 19
    // layer 1
    k_mgemm<<<gL, 256, 0, stream>>>(Eb, sEb, KD, Wl1t, KD, bl1, MAXM, HC, KD,
                                    nullptr, 0, 0, Xl, sXb, KHC);
    k_mgemm<<<gL, 256, 0, stream>>>(Eb, sEb, KD, Wr1t, KD, br1, MAXM, HC, KD,
                                    nullptr, 0, 0, Xr, sXb, KHC);
    k_att<<<dim3(MAXM, B), 256, 0, stream>>>(Xl, Xr, deg, off, csr, att1, bias1, Hb);
    // layer 2
    k_mgemm<<<gL, 256, 0, stream>>>(Hb, sXb, KHC, Wl2t, KHC, bl2, MAXM, HC, KHC,
                                    nullptr, 0, 0, Xl, sXb, KHC);
    k_mgemm<<<gL, 256, 0, stream>>>(Hb, sXb, KHC, Wr2t, KHC, br2, MAXM, HC, KHC,
                                    nullptr, 0, 0, Xr, sXb, KHC);
    k_att<<<dim3(MAXM, B), 256, 0, stream>>>(Xl, Xr, deg, off, csr, att2, bias2, Hb);
    // projections
    dim3 gP(3, 19, B);
    k_mgemm<<<gP, 256, 0, stream>>>(Hb, sXb, KHC, Wp1t, KHC, bp1, MAXM, C, KHC,
                                    nullptr, 0, 0, T1b, sEb, KD);
    k_mgemm<<<gP, 256, 0, stream>>>(T1b, sEb, KD, Wp2t, KD, bp2, MAXM, C, KD,
                                    nullptr, 0, 0, wb, sWb, WB_LD);
    // final
    k_fgather<<<dim3(T, B), 256, 0, stream>>>(wb, tric, Af);
    k_mgemm<<<dim3(6, 7, B), 256, 0, stream>>>(Af, sAf, KF, Wft, KF, nullptr, T, 768, KF,
                                               out, (long)T * 768, 768, nullptr, 0, 0);
}

// Round 3
// 361.967 us; speedup vs baseline: 5.0785x; 1.3512x over previous
//
#include <hip/hip_runtime.h>
#include <hip/hip_bf16.h>

#define V 30000
#define D 300
#define H 4
#define C 300
#define HC 1200
#define B 2
#define T 800
#define E 1600          // real edges per sample
#define MAXM 2400       // max unique nodes per sample
#define NEG 0.2f
#define SCAN_CH ((MAXM + 255) / 256)

#define MR 2432         // node rows padded to 128-multiple (19*128)
#define KD 320          // D padded to 32-multiple
#define KHC 1216        // HC padded to 32-multiple
#define NLR 2432        // combined Wl|Wr output cols: [0,1200) xl, [1216,2416) xr, pads 0
#define WB_LD 304       // w bf16 leading dim
#define KF 928          // 900 padded
#define FRW 896         // T rows padded (7*128)

typedef __attribute__((ext_vector_type(8))) unsigned short u16x8;
typedef __attribute__((ext_vector_type(8))) short s16x8;
typedef __attribute__((ext_vector_type(4))) float f32x4;

__device__ inline unsigned short f2b(float v) {
    unsigned u = __float_as_uint(v);
    unsigned r = (u + 0x7FFFu + ((u >> 16) & 1u)) >> 16;
    return (unsigned short)r;
}
__device__ inline float b2f(unsigned short u) {
    return __uint_as_float(((unsigned)u) << 16);
}

// ---------------- graph build ----------------

__global__ void k_init(int* map, int* list, int* deg, int* fill, int* mcnt) {
    int i = blockIdx.x * blockDim.x + threadIdx.x;
    if (i < B * V) map[i] = -1;
    if (i < B * MAXM) { list[i] = 0; deg[i] = 0; fill[i] = 0; }
    if (i < B) mcnt[i] = 0;
}

__global__ void k_mark(const int* __restrict__ kg, int* map) {
    int i = blockIdx.x * blockDim.x + threadIdx.x;
    if (i >= B * T * 3) return;
    int b = i / (T * 3);
    map[b * V + kg[i]] = 1;
}

// ballot-aggregated compaction: one atomic per block (Guideline 12)
__global__ void k_compact(int* map, int* list, int* mcnt) {
    int b = blockIdx.y;
    int i = blockIdx.x * 256 + threadIdx.x;
    bool pred = (i < V) && (map[b * V + i] == 1);
    unsigned long long m = __ballot(pred);
    int lane = threadIdx.x & 63;
    int wid = threadIdx.x >> 6;
    __shared__ int wcnt[4];
    __shared__ int base;
    if (lane == 0) wcnt[wid] = __popcll(m);
    __syncthreads();
    if (threadIdx.x == 0) {
        int t = 0;
#pragma unroll
        for (int w2 = 0; w2 < 4; ++w2) { int c = wcnt[w2]; wcnt[w2] = t; t += c; }
        base = t ? atomicAdd(&mcnt[b], t) : 0;
    }
    __syncthreads();
    if (pred) {
        int idx = base + wcnt[wid] + __popcll(m & ((1ull << lane) - 1ull));
        map[b * V + i] = idx;
        list[b * MAXM + idx] = i;
    }
}

__global__ void k_edges(const int* __restrict__ kg, const int* __restrict__ map,
                        int* esrc, int* edst, int* deg, int* tric) {
    int i = blockIdx.x * blockDim.x + threadIdx.x;
    if (i >= B * T) return;
    int b = i / T, t = i % T;
    const int* kk = kg + ((long)b * T + t) * 3;
    int hc = map[b * V + kk[0]];
    int rc = map[b * V + kk[1]];
    int tc = map[b * V + kk[2]];
    int eb = b * E;
    esrc[eb + t]     = hc;  edst[eb + t]     = rc;
    esrc[eb + T + t] = rc;  edst[eb + T + t] = tc;
    atomicAdd(&deg[b * MAXM + rc], 1);
    atomicAdd(&deg[b * MAXM + tc], 1);
    int* tr = tric + ((long)b * T + t) * 3;
    tr[0] = hc; tr[1] = rc; tr[2] = tc;
}

__global__ void k_scan(const int* __restrict__ deg, int* __restrict__ off) {
    int b = blockIdx.x;
    deg += b * MAXM; off += b * (MAXM + 1);
    __shared__ int ts[256];
    int t = threadIdx.x;
    int base = t * SCAN_CH;
    int loc[SCAN_CH];
    int sum = 0;
#pragma unroll
    for (int j = 0; j < SCAN_CH; ++j) {
        int v = (base + j < MAXM) ? deg[base + j] : 0;
        sum += v; loc[j] = sum;
    }
    ts[t] = sum; __syncthreads();
    for (int s = 1; s < 256; s <<= 1) {
        int v = (t >= s) ? ts[t - s] : 0;
        __syncthreads();
        ts[t] += v;
        __syncthreads();
    }
    int excl = (t > 0) ? ts[t - 1] : 0;
#pragma unroll
    for (int j = 0; j < SCAN_CH; ++j)
        if (base + j < MAXM) off[base + j + 1] = excl + loc[j];
    if (t == 0) off[0] = 0;
}

__global__ void k_scatter(const int* __restrict__ esrc, const int* __restrict__ edst,
                          const int* __restrict__ off, int* fill, int* csr) {
    int i = blockIdx.x * blockDim.x + threadIdx.x;
    if (i >= B * E) return;
    int b = i / E;
    int d = edst[i];
    int pos = off[b * (MAXM + 1) + d] + atomicAdd(&fill[b * MAXM + d], 1);
    csr[b * E + pos] = esrc[i];
}

// ---------------- fused weight transposes f32 [K][N] -> bf16 [Ncover][Kp] ----------------
__global__ void k_wt_all(const float* __restrict__ Wl1, const float* __restrict__ Wr1,
                         const float* __restrict__ Wl2, const float* __restrict__ Wr2,
                         const float* __restrict__ Wp1, const float* __restrict__ Wp2,
                         const float* __restrict__ Wlii,
                         unsigned short* Wlr1t, unsigned short* Wlr2t,
                         unsigned short* Wp1t, unsigned short* Wp2t, unsigned short* Wft) {
    const int KT[7]  = {10, 10, 38, 38, 38, 10, 29};
    const int CUM[8] = {0, 380, 760, 2204, 3648, 4104, 4224, 4920};
    int bid = blockIdx.x;
    int task = 0;
    while (bid >= CUM[task + 1]) ++task;
    int local = bid - CUM[task];
    int kt = local % KT[task], nt = local / KT[task];
    const float* W; unsigned short* Wt; int K, N, Kp;
    switch (task) {
        case 0: W = Wl1;  Wt = Wlr1t;                     K = 300;  N = 1200; Kp = KD;  break;
        case 1: W = Wr1;  Wt = Wlr1t + (long)1216 * KD;   K = 300;  N = 1200; Kp = KD;  break;
        case 2: W = Wl2;  Wt = Wlr2t;                     K = 1200; N = 1200; Kp = KHC; break;
        case 3: W = Wr2;  Wt = Wlr2t + (long)1216 * KHC;  K = 1200; N = 1200; Kp = KHC; break;
        case 4: W = Wp1;  Wt = Wp1t;                      K = 1200; N = 300;  Kp = KHC; break;
        case 5: W = Wp2;  Wt = Wp2t;                      K = 300;  N = 300;  Kp = KD;  break;
        default: W = Wlii; Wt = Wft;                      K = 900;  N = 768;  Kp = KF;  break;
    }
    __shared__ float t[32][33];
    int k0 = kt * 32, n0 = nt * 32;
    int tx = threadIdx.x, ty = threadIdx.y;
#pragma unroll
    for (int p = 0; p < 4; ++p) {
        int k = k0 + ty + p * 8, n = n0 + tx;
        t[ty + p * 8][tx] = (k < K && n < N) ? W[(long)k * N + n] : 0.f;
    }
    __syncthreads();
#pragma unroll
    for (int p = 0; p < 4; ++p) {
        int n = n0 + ty + p * 8, k = k0 + tx;
        Wt[(long)n * Kp + k] = f2b(t[tx][ty + p * 8]);
    }
}

// combined biases for the Wl|Wr fused GEMMs
__global__ void k_biases(const float* __restrict__ bl1, const float* __restrict__ br1,
                         const float* __restrict__ bl2, const float* __restrict__ br2,
                         float* blr1, float* blr2) {
    int c = blockIdx.x * 256 + threadIdx.x;
    if (c >= NLR) return;
    float v1 = 0.f, v2 = 0.f;
    if (c < 1200) { v1 = bl1[c]; v2 = bl2[c]; }
    else if (c >= 1216 && c < 2416) { v1 = br1[c - 1216]; v2 = br2[c - 1216]; }
    blr1[c] = v1; blr2[c] = v2;
}

// ---------------- embedding gather f32 -> bf16 padded ----------------
__global__ void k_embgather(const float* __restrict__ emb, const int* __restrict__ list,
                            unsigned short* __restrict__ Eb) {
    int b = blockIdx.y, i = blockIdx.x;
    int src = list[b * MAXM + i];
    const float* e = emb + (long)src * D;
    unsigned short* o = Eb + ((long)b * MR + i) * KD;
    for (int c = threadIdx.x; c < KD; c += 256)
        o[c] = (c < D) ? f2b(e[c]) : 0;
}

// ---------------- bf16 MFMA GEMM ----------------
__global__ __launch_bounds__(256) void k_mgemm(
    const unsigned short* __restrict__ A, long sA, int lda,
    const unsigned short* __restrict__ Wt, int ldw,
    const float* __restrict__ bias,
    int M, int N, int K,
    float* __restrict__ outF, long sF, int ldf,
    unsigned short* __restrict__ outB, long sB, int ldb_) {
    int b = blockIdx.z;
    A += (long)b * sA;
    __shared__ unsigned short As[128][40];
    __shared__ unsigned short Bs[128][40];
    int tid = threadIdx.x;
    int m0 = blockIdx.y * 128, n0 = blockIdx.x * 128;
    int w = tid >> 6, lane = tid & 63;
    int wr = (w >> 1) * 64, wc = (w & 1) * 64;
    int fr = lane & 15, fq = lane >> 4;
    int r0 = tid >> 2, sg = tid & 3;
    const unsigned short* Ap  = A  + (long)(m0 + r0) * lda + sg * 8;
    const unsigned short* Ap2 = A  + (long)(m0 + r0 + 64) * lda + sg * 8;
    const unsigned short* Bp  = Wt + (long)(n0 + r0) * ldw + sg * 8;
    const unsigned short* Bp2 = Wt + (long)(n0 + r0 + 64) * ldw + sg * 8;
    f32x4 acc[4][4] = {};
    for (int k0 = 0; k0 < K; k0 += 32) {
        *(u16x8*)&As[r0][sg * 8]      = *(const u16x8*)(Ap + k0);
        *(u16x8*)&As[r0 + 64][sg * 8] = *(const u16x8*)(Ap2 + k0);
        *(u16x8*)&Bs[r0][sg * 8]      = *(const u16x8*)(Bp + k0);
        *(u16x8*)&Bs[r0 + 64][sg * 8] = *(const u16x8*)(Bp2 + k0);
        __syncthreads();
        s16x8 af[4], bfr[4];
#pragma unroll
        for (int m = 0; m < 4; ++m)
            af[m] = *(const s16x8*)&As[wr + m * 16 + fr][fq * 8];
#pragma unroll
        for (int n = 0; n < 4; ++n)
            bfr[n] = *(const s16x8*)&Bs[wc + n * 16 + fr][fq * 8];
#pragma unroll
        for (int m = 0; m < 4; ++m)
#pragma unroll
            for (int n = 0; n < 4; ++n)
                acc[m][n] = __builtin_amdgcn_mfma_f32_16x16x32_bf16(af[m], bfr[n], acc[m][n], 0, 0, 0);
        __syncthreads();
    }
    float* oF = outF ? outF + (long)b * sF : nullptr;
    unsigned short* oB = outB ? outB + (long)b * sB : nullptr;
#pragma unroll
    for (int m = 0; m < 4; ++m) {
        int rb = m0 + wr + m * 16 + fq * 4;
#pragma unroll
        for (int n = 0; n < 4; ++n) {
            int col = n0 + wc + n * 16 + fr;
#pragma unroll
            for (int j = 0; j < 4; ++j) {
                int row = rb + j;
                if (row >= M) continue;
                if (col < N) {
                    float v = acc[m][n][j] + (bias ? bias[col] : 0.f);
                    if (oF) oF[(long)row * ldf + col] = v;
                    if (oB) oB[(long)row * ldb_ + col] = f2b(v);
                } else if (oB && col < ldb_) {
                    oB[(long)row * ldb_ + col] = 0;
                }
            }
        }
    }
}

// ---------------- GATv2 attention: single-pass online softmax ----------------
// XLR: [B][MR][NLR] bf16, xl = cols [0,1216), xr = cols [1216,2432)
__global__ __launch_bounds__(256) void k_att(
    const unsigned short* __restrict__ XLR,
    const int* __restrict__ deg, const int* __restrict__ off, const int* __restrict__ csr,
    const float* __restrict__ att, const float* __restrict__ bias,
    unsigned short* __restrict__ OUT) {
    const long sX = (long)MR * NLR;
    const long sO = (long)MR * KHC;
    int b = blockIdx.y;
    int i = blockIdx.x;
    const unsigned short* xl = XLR + (long)b * sX;
    const unsigned short* xr = xl + 1216;
    unsigned short* out = OUT + (long)b * sO;
    int lane = threadIdx.x & 63;
    int h = threadIdx.x >> 6;

    float xr_reg[5], att_reg[5];
#pragma unroll
    for (int q = 0; q < 5; ++q) {
        int c = lane + q * 64;
        if (c < C) {
            xr_reg[q] = b2f(xr[(long)i * NLR + h * C + c]);
            att_reg[q] = att[h * C + c];
        } else { xr_reg[q] = 0.f; att_reg[q] = 0.f; }
    }
    int dg = deg[b * MAXM + i];
    int o0 = off[b * (MAXM + 1) + i];
    const int* cs = csr + b * E;

    float mx = -3e38f, den = 0.f;
    float acc[5] = {0.f, 0.f, 0.f, 0.f, 0.f};
    auto step = [&](int s) {
        const unsigned short* xls = xl + (long)s * NLR + h * C;
        float part = 0.f;
        float xlv[5];
#pragma unroll
        for (int q = 0; q < 5; ++q) {
            int c = lane + q * 64;
            if (c < C) {
                float xv = b2f(xls[c]);
                xlv[q] = xv;
                float v = xv + xr_reg[q];
                v = v > 0.f ? v : NEG * v;
                part += att_reg[q] * v;
            } else xlv[q] = 0.f;
        }
#pragma unroll
        for (int m = 1; m < 64; m <<= 1) part += __shfl_xor(part, m);
        float mn = fmaxf(mx, part);
        float sc = __expf(mx - mn);
        float p = __expf(part - mn);
        den = den * sc + p;
#pragma unroll
        for (int q = 0; q < 5; ++q) acc[q] = acc[q] * sc + p * xlv[q];
        mx = mn;
    };
    step(i);
    for (int e = 0; e < dg; ++e) step(cs[o0 + e]);

    float inv = 1.f / den;
#pragma unroll
    for (int q = 0; q < 5; ++q) {
        int c = lane + q * 64;
        if (c < C) {
            float v = acc[q] * inv + bias[h * C + c];
            out[(long)i * KHC + h * C + c] = f2b(v > 0.f ? v : 0.f);
        }
    }
    if (h == 0 && lane < KHC - HC)
        out[(long)i * KHC + HC + lane] = 0;
}

// ---------------- final A gather: concat(w[h],w[r],w[t]) bf16 padded ----------------
__global__ void k_fgather(const unsigned short* __restrict__ wb, const int* __restrict__ tric,
                          unsigned short* __restrict__ Af) {
    int b = blockIdx.y, t = blockIdx.x;
    const int* tr = tric + ((long)b * T + t) * 3;
    const unsigned short* w = wb + (long)b * (long)MR * WB_LD;
    unsigned short* o = Af + ((long)b * FRW + t) * KF;
    for (int c = threadIdx.x; c < KF; c += 256) {
        if (c < 900) {
            int part = c / 300, kc = c - part * 300;
            o[c] = w[(long)tr[part] * WB_LD + kc];
        } else o[c] = 0;
    }
}

extern "C" void kernel_launch(void* const* d_in, const int* in_sizes, int n_in,
                              void* d_out, int out_size, void* d_ws, size_t ws_size,
                              hipStream_t stream) {
    const int*   kg    = (const int*)d_in[0];
    const float* emb   = (const float*)d_in[1];
    const float* Wl1   = (const float*)d_in[2];
    const float* bl1   = (const float*)d_in[3];
    const float* Wr1   = (const float*)d_in[4];
    const float* br1   = (const float*)d_in[5];
    const float* att1  = (const float*)d_in[6];
    const float* bias1 = (const float*)d_in[7];
    const float* Wl2   = (const float*)d_in[8];
    const float* bl2   = (const float*)d_in[9];
    const float* Wr2   = (const float*)d_in[10];
    const float* br2   = (const float*)d_in[11];
    const float* att2  = (const float*)d_in[12];
    const float* bias2 = (const float*)d_in[13];
    const float* Wp1   = (const float*)d_in[14];
    const float* bp1   = (const float*)d_in[15];
    const float* Wp2   = (const float*)d_in[16];
    const float* bp2   = (const float*)d_in[17];
    const float* Wlii  = (const float*)d_in[18];
    float* out = (float*)d_out;

    char* ws = (char*)d_ws;
    size_t o = 0;
    auto alloc = [&](size_t bytes) -> void* {
        void* p = ws + o;
        o = (o + bytes + 255) & ~(size_t)255;
        return p;
    };
    int* map  = (int*)alloc(sizeof(int) * B * V);
    int* list = (int*)alloc(sizeof(int) * B * MAXM);
    int* mcnt = (int*)alloc(sizeof(int) * B);
    int* deg  = (int*)alloc(sizeof(int) * B * MAXM);
    int* off  = (int*)alloc(sizeof(int) * B * (MAXM + 1));
    int* fill = (int*)alloc(sizeof(int) * B * MAXM);
    int* esrc = (int*)alloc(sizeof(int) * B * E);
    int* edst = (int*)alloc(sizeof(int) * B * E);
    int* csr  = (int*)alloc(sizeof(int) * B * E);
    int* tric = (int*)alloc(sizeof(int) * B * T * 3);

    long sXlr = (long)MR * NLR;
    long sHb  = (long)MR * KHC;
    long sEb  = (long)MR * KD;
    unsigned short* Xlr = (unsigned short*)alloc(2LL * B * sXlr);   // also aliased as Af
    unsigned short* Hb  = (unsigned short*)alloc(2LL * B * sHb);    // also aliased as wb
    unsigned short* Eb  = (unsigned short*)alloc(2LL * B * sEb);    // also aliased as T1b

    unsigned short* Wlr1t = (unsigned short*)alloc(2LL * 2432 * KD);
    unsigned short* Wlr2t = (unsigned short*)alloc(2LL * 2432 * KHC);
    unsigned short* Wp1t  = (unsigned short*)alloc(2LL * 384 * KHC);
    unsigned short* Wp2t  = (unsigned short*)alloc(2LL * 384 * KD);
    unsigned short* Wft   = (unsigned short*)alloc(2LL * 768 * KF);
    float* blr1 = (float*)alloc(sizeof(float) * NLR);
    float* blr2 = (float*)alloc(sizeof(float) * NLR);
    (void)ws_size; (void)in_sizes; (void)n_in; (void)out_size;

    unsigned short* T1b = Eb;    // [B][MR][KD]   (Eb dead after layer-1 GEMM)
    unsigned short* wb  = Hb;    // [B][MR][WB_LD] (Hb dead after proj1)
    unsigned short* Af  = Xlr;   // [B][FRW][KF]   (Xlr dead after att2)

    // graph
    k_init<<<(B * V + 255) / 256, 256, 0, stream>>>(map, list, deg, fill, mcnt);
    k_mark<<<(B * T * 3 + 255) / 256, 256, 0, stream>>>(kg, map);
    k_compact<<<dim3((V + 255) / 256, B), 256, 0, stream>>>(map, list, mcnt);
    k_edges<<<(B * T + 255) / 256, 256, 0, stream>>>(kg, map, esrc, edst, deg, tric);
    k_scan<<<B, 256, 0, stream>>>(deg, off);
    k_scatter<<<(B * E + 255) / 256, 256, 0, stream>>>(esrc, edst, off, fill, csr);

    // weights -> bf16 transposed (fused) + combined biases
    k_wt_all<<<4920, dim3(32, 8), 0, stream>>>(Wl1, Wr1, Wl2, Wr2, Wp1, Wp2, Wlii,
                                               Wlr1t, Wlr2t, Wp1t, Wp2t, Wft);
    k_biases<<<(NLR + 255) / 256, 256, 0, stream>>>(bl1, br1, bl2, br2, blr1, blr2);

    // embedding gather
    k_embgather<<<dim3(MAXM, B), 256, 0, stream>>>(emb, list, Eb);

    long sWb = (long)MR * WB_LD;
    long sAf = (long)FRW * KF;

    dim3 gL(19, 19, B);   // N=2432 -> 19 tiles, M=2432 -> 19 tiles
    // layer 1 (combined Wl|Wr)
    k_mgemm<<<gL, 256, 0, stream>>>(Eb, sEb, KD, Wlr1t, KD, blr1, MAXM, NLR, KD,
                                    nullptr, 0, 0, Xlr, sXlr, NLR);
    k_att<<<dim3(MAXM, B), 256, 0, stream>>>(Xlr, deg, off, csr, att1, bias1, Hb);
    // layer 2 (combined)
    k_mgemm<<<gL, 256, 0, stream>>>(Hb, sHb, KHC, Wlr2t, KHC, blr2, MAXM, NLR, KHC,
                                    nullptr, 0, 0, Xlr, sXlr, NLR);
    k_att<<<dim3(MAXM, B), 256, 0, stream>>>(Xlr, deg, off, csr, att2, bias2, Hb);
    // projections
    dim3 gP(3, 19, B);
    k_mgemm<<<gP, 256, 0, stream>>>(Hb, sHb, KHC, Wp1t, KHC, bp1, MAXM, C, KHC,
                                    nullptr, 0, 0, T1b, sEb, KD);
    k_mgemm<<<gP, 256, 0, stream>>>(T1b, sEb, KD, Wp2t, KD, bp2, MAXM, C, KD,
                                    nullptr, 0, 0, wb, sWb, WB_LD);
    // final
    k_fgather<<<dim3(T, B), 256, 0, stream>>>(wb, tric, Af);
    k_mgemm<<<dim3(6, 7, B), 256, 0, stream>>>(Af, sAf, KF, Wft, KF, nullptr, T, 768, KF,
                                               out, (long)T * 768, 768, nullptr, 0, 0);
}

// Round 4
// 349.809 us; speedup vs baseline: 5.2550x; 1.0348x over previous
//
#include <hip/hip_runtime.h>
#include <hip/hip_bf16.h>

#define V 30000
#define D 300
#define H 4
#define C 300
#define HC 1200
#define B 2
#define T 800
#define E 1600          // real edges per sample
#define MAXM 2400       // max unique nodes per sample
#define NEG 0.2f
#define SCAN_CH ((MAXM + 255) / 256)

#define MR 2432         // node rows padded to 128-multiple (19*128)
#define KD 320          // D padded to 32-multiple
#define KHC 1216        // HC padded to 32-multiple
#define NLR 2432        // combined Wl|Wr output cols: [0,1200) xl, [1216,2416) xr, pads 0
#define WB_LD 304       // w bf16 leading dim
#define KF 928          // 900 padded
#define FRW 896         // T rows padded (7*128)

typedef __attribute__((ext_vector_type(8))) unsigned short u16x8;
typedef __attribute__((ext_vector_type(8))) short s16x8;
typedef __attribute__((ext_vector_type(4))) float f32x4;

__device__ inline unsigned short f2b(float v) {
    unsigned u = __float_as_uint(v);
    unsigned r = (u + 0x7FFFu + ((u >> 16) & 1u)) >> 16;
    return (unsigned short)r;
}
__device__ inline float b2f(unsigned short u) {
    return __uint_as_float(((unsigned)u) << 16);
}

// async global->LDS, 16B per lane (m97 pattern; dest must be linear in tid per wave)
#define GLOAD_LDS16(g, l) __builtin_amdgcn_global_load_lds( \
    (const __attribute__((address_space(1))) void*)(g), \
    (__attribute__((address_space(3))) void*)(l), 16, 0, 0)

// ---------------- graph build ----------------

__global__ void k_init(int* map, int* list, int* deg, int* fill, int* mcnt) {
    int i = blockIdx.x * blockDim.x + threadIdx.x;
    if (i < B * V) map[i] = -1;
    if (i < B * MAXM) { list[i] = 0; deg[i] = 0; fill[i] = 0; }
    if (i < B) mcnt[i] = 0;
}

__global__ void k_mark(const int* __restrict__ kg, int* map) {
    int i = blockIdx.x * blockDim.x + threadIdx.x;
    if (i >= B * T * 3) return;
    int b = i / (T * 3);
    map[b * V + kg[i]] = 1;
}

// ballot-aggregated compaction: one atomic per block (Guideline 12)
__global__ void k_compact(int* map, int* list, int* mcnt) {
    int b = blockIdx.y;
    int i = blockIdx.x * 256 + threadIdx.x;
    bool pred = (i < V) && (map[b * V + i] == 1);
    unsigned long long m = __ballot(pred);
    int lane = threadIdx.x & 63;
    int wid = threadIdx.x >> 6;
    __shared__ int wcnt[4];
    __shared__ int base;
    if (lane == 0) wcnt[wid] = __popcll(m);
    __syncthreads();
    if (threadIdx.x == 0) {
        int t = 0;
#pragma unroll
        for (int w2 = 0; w2 < 4; ++w2) { int c = wcnt[w2]; wcnt[w2] = t; t += c; }
        base = t ? atomicAdd(&mcnt[b], t) : 0;
    }
    __syncthreads();
    if (pred) {
        int idx = base + wcnt[wid] + __popcll(m & ((1ull << lane) - 1ull));
        map[b * V + i] = idx;
        list[b * MAXM + idx] = i;
    }
}

__global__ void k_edges(const int* __restrict__ kg, const int* __restrict__ map,
                        int* esrc, int* edst, int* deg, int* tric) {
    int i = blockIdx.x * blockDim.x + threadIdx.x;
    if (i >= B * T) return;
    int b = i / T, t = i % T;
    const int* kk = kg + ((long)b * T + t) * 3;
    int hc = map[b * V + kk[0]];
    int rc = map[b * V + kk[1]];
    int tc = map[b * V + kk[2]];
    int eb = b * E;
    esrc[eb + t]     = hc;  edst[eb + t]     = rc;
    esrc[eb + T + t] = rc;  edst[eb + T + t] = tc;
    atomicAdd(&deg[b * MAXM + rc], 1);
    atomicAdd(&deg[b * MAXM + tc], 1);
    int* tr = tric + ((long)b * T + t) * 3;
    tr[0] = hc; tr[1] = rc; tr[2] = tc;
}

__global__ void k_scan(const int* __restrict__ deg, int* __restrict__ off) {
    int b = blockIdx.x;
    deg += b * MAXM; off += b * (MAXM + 1);
    __shared__ int ts[256];
    int t = threadIdx.x;
    int base = t * SCAN_CH;
    int loc[SCAN_CH];
    int sum = 0;
#pragma unroll
    for (int j = 0; j < SCAN_CH; ++j) {
        int v = (base + j < MAXM) ? deg[base + j] : 0;
        sum += v; loc[j] = sum;
    }
    ts[t] = sum; __syncthreads();
    for (int s = 1; s < 256; s <<= 1) {
        int v = (t >= s) ? ts[t - s] : 0;
        __syncthreads();
        ts[t] += v;
        __syncthreads();
    }
    int excl = (t > 0) ? ts[t - 1] : 0;
#pragma unroll
    for (int j = 0; j < SCAN_CH; ++j)
        if (base + j < MAXM) off[base + j + 1] = excl + loc[j];
    if (t == 0) off[0] = 0;
}

__global__ void k_scatter(const int* __restrict__ esrc, const int* __restrict__ edst,
                          const int* __restrict__ off, int* fill, int* csr) {
    int i = blockIdx.x * blockDim.x + threadIdx.x;
    if (i >= B * E) return;
    int b = i / E;
    int d = edst[i];
    int pos = off[b * (MAXM + 1) + d] + atomicAdd(&fill[b * MAXM + d], 1);
    csr[b * E + pos] = esrc[i];
}

// ---------------- fused weight transposes + combined biases ----------------
__global__ void k_wt_all(const float* __restrict__ Wl1, const float* __restrict__ Wr1,
                         const float* __restrict__ Wl2, const float* __restrict__ Wr2,
                         const float* __restrict__ Wp1, const float* __restrict__ Wp2,
                         const float* __restrict__ Wlii,
                         const float* __restrict__ bl1, const float* __restrict__ br1,
                         const float* __restrict__ bl2, const float* __restrict__ br2,
                         unsigned short* Wlr1t, unsigned short* Wlr2t,
                         unsigned short* Wp1t, unsigned short* Wp2t, unsigned short* Wft,
                         float* blr1, float* blr2) {
    const int KT[7]  = {10, 10, 38, 38, 38, 10, 29};
    const int CUM[9] = {0, 380, 760, 2204, 3648, 4104, 4224, 4920, 4930};
    int bid = blockIdx.x;
    int task = 0;
    while (bid >= CUM[task + 1]) ++task;
    int local = bid - CUM[task];
    if (task == 7) {   // combined biases
        int c = local * 256 + threadIdx.y * 32 + threadIdx.x;
        if (c < NLR) {
            float v1 = 0.f, v2 = 0.f;
            if (c < 1200) { v1 = bl1[c]; v2 = bl2[c]; }
            else if (c >= 1216 && c < 2416) { v1 = br1[c - 1216]; v2 = br2[c - 1216]; }
            blr1[c] = v1; blr2[c] = v2;
        }
        return;
    }
    int kt = local % KT[task], nt = local / KT[task];
    const float* W; unsigned short* Wt; int K, N, Kp;
    switch (task) {
        case 0: W = Wl1;  Wt = Wlr1t;                     K = 300;  N = 1200; Kp = KD;  break;
        case 1: W = Wr1;  Wt = Wlr1t + (long)1216 * KD;   K = 300;  N = 1200; Kp = KD;  break;
        case 2: W = Wl2;  Wt = Wlr2t;                     K = 1200; N = 1200; Kp = KHC; break;
        case 3: W = Wr2;  Wt = Wlr2t + (long)1216 * KHC;  K = 1200; N = 1200; Kp = KHC; break;
        case 4: W = Wp1;  Wt = Wp1t;                      K = 1200; N = 300;  Kp = KHC; break;
        case 5: W = Wp2;  Wt = Wp2t;                      K = 300;  N = 300;  Kp = KD;  break;
        default: W = Wlii; Wt = Wft;                      K = 900;  N = 768;  Kp = KF;  break;
    }
    __shared__ float t[32][33];
    int k0 = kt * 32, n0 = nt * 32;
    int tx = threadIdx.x, ty = threadIdx.y;
#pragma unroll
    for (int p = 0; p < 4; ++p) {
        int k = k0 + ty + p * 8, n = n0 + tx;
        t[ty + p * 8][tx] = (k < K && n < N) ? W[(long)k * N + n] : 0.f;
    }
    __syncthreads();
#pragma unroll
    for (int p = 0; p < 4; ++p) {
        int n = n0 + ty + p * 8, k = k0 + tx;
        Wt[(long)n * Kp + k] = f2b(t[tx][ty + p * 8]);
    }
}

// ---------------- embedding gather f32 -> bf16 padded (vectorized, G13) ----------------
__global__ void k_embgather(const float* __restrict__ emb, const int* __restrict__ list,
                            unsigned short* __restrict__ Eb) {
    int b = blockIdx.y, i = blockIdx.x;
    int src = list[b * MAXM + i];
    const float* e = emb + (long)src * D;
    unsigned short* o = Eb + ((long)b * MR + i) * KD;
    int c = threadIdx.x;
    if (c < 75) {
        float4 v = *(const float4*)(e + c * 4);
        ushort4 u;
        u.x = f2b(v.x); u.y = f2b(v.y); u.z = f2b(v.z); u.w = f2b(v.w);
        *(ushort4*)(o + c * 4) = u;
    } else if (c < 80) {
        *(ushort4*)(o + c * 4) = make_ushort4(0, 0, 0, 0);
    }
}

// ---------------- bf16 MFMA GEMM (global_load_lds + XOR-swizzled LDS + L2 block swizzle) --
__global__ __launch_bounds__(256) void k_mgemm(
    const unsigned short* __restrict__ A, long sA, int lda,
    const unsigned short* __restrict__ Wt, int ldw,
    const float* __restrict__ bias,
    int M, int N, int K,
    float* __restrict__ outF, long sF, int ldf,
    unsigned short* __restrict__ outB, long sB, int ldb_) {
    int b = blockIdx.z;
    A += (long)b * sA;
    __shared__ unsigned short As[128][32];   // 64 B rows; chunk c holds global chunk c^((r>>1)&3)
    __shared__ unsigned short Bs[128][32];
    int tid = threadIdx.x;

    // bijective XCD chunking (m204) + group-M decode for L2 locality
    int nbx = gridDim.x, nby = gridDim.y;
    int nwg = nbx * nby;
    int wg = blockIdx.y * nbx + blockIdx.x;
    int q = nwg >> 3, r8 = nwg & 7;
    int xcd = wg & 7, idx = wg >> 3;
    int L = (xcd < r8 ? xcd * (q + 1) : r8 * (q + 1) + (xcd - r8) * q) + idx;
    const int G = 4;
    int band = L / (G * nbx);
    int first = band * G;
    int sz = min(G, nby - first);
    int rem = L - band * G * nbx;
    int by = first + rem % sz;
    int bx = rem / sz;
    int m0 = by * 128, n0 = bx * 128;

    int w = tid >> 6, lane = tid & 63;
    int wr = (w >> 1) * 64, wc = (w & 1) * 64;
    int fr = lane & 15, fq = lane >> 4;
    int r0 = tid >> 2, sg = tid & 3;
    int swz = (sg ^ ((r0 >> 1) & 3)) * 8;   // pre-swizzled global chunk (involution)
    const unsigned short* Ap  = A  + (long)(m0 + r0) * lda + swz;
    const unsigned short* Ap2 = A  + (long)(m0 + r0 + 64) * lda + swz;
    const unsigned short* Bp  = Wt + (long)(n0 + r0) * ldw + swz;
    const unsigned short* Bp2 = Wt + (long)(n0 + r0 + 64) * ldw + swz;
    unsigned short* lA  = &As[r0][sg * 8];          // byte offset tid*16: linear per wave
    unsigned short* lA2 = &As[r0 + 64][sg * 8];
    unsigned short* lB  = &Bs[r0][sg * 8];
    unsigned short* lB2 = &Bs[r0 + 64][sg * 8];

    f32x4 acc[4][4] = {};
    for (int k0 = 0; k0 < K; k0 += 32) {
        GLOAD_LDS16(Ap + k0, lA);
        GLOAD_LDS16(Ap2 + k0, lA2);
        GLOAD_LDS16(Bp + k0, lB);
        GLOAD_LDS16(Bp2 + k0, lB2);
        __syncthreads();   // drains vmcnt before barrier
        s16x8 af[4], bfr[4];
#pragma unroll
        for (int m = 0; m < 4; ++m) {
            int rr = wr + m * 16 + fr;
            af[m] = *(const s16x8*)&As[rr][(fq ^ ((rr >> 1) & 3)) * 8];
        }
#pragma unroll
        for (int n = 0; n < 4; ++n) {
            int rr = wc + n * 16 + fr;
            bfr[n] = *(const s16x8*)&Bs[rr][(fq ^ ((rr >> 1) & 3)) * 8];
        }
#pragma unroll
        for (int m = 0; m < 4; ++m)
#pragma unroll
            for (int n = 0; n < 4; ++n)
                acc[m][n] = __builtin_amdgcn_mfma_f32_16x16x32_bf16(af[m], bfr[n], acc[m][n], 0, 0, 0);
        __syncthreads();
    }
    float* oF = outF ? outF + (long)b * sF : nullptr;
    unsigned short* oB = outB ? outB + (long)b * sB : nullptr;
#pragma unroll
    for (int m = 0; m < 4; ++m) {
        int rb = m0 + wr + m * 16 + fq * 4;
#pragma unroll
        for (int n = 0; n < 4; ++n) {
            int col = n0 + wc + n * 16 + fr;
#pragma unroll
            for (int j = 0; j < 4; ++j) {
                int row = rb + j;
                if (row >= M) continue;
                if (col < N) {
                    float v = acc[m][n][j] + (bias ? bias[col] : 0.f);
                    if (oF) oF[(long)row * ldf + col] = v;
                    if (oB) oB[(long)row * ldb_ + col] = f2b(v);
                } else if (oB && col < ldb_) {
                    oB[(long)row * ldb_ + col] = 0;
                }
            }
        }
    }
}

// ---------------- GATv2 attention: single-pass online softmax ----------------
// XLR: [B][MR][NLR] bf16, xl = cols [0,1216), xr = cols [1216,2432)
__global__ __launch_bounds__(256) void k_att(
    const unsigned short* __restrict__ XLR,
    const int* __restrict__ deg, const int* __restrict__ off, const int* __restrict__ csr,
    const float* __restrict__ att, const float* __restrict__ bias,
    unsigned short* __restrict__ OUT) {
    const long sX = (long)MR * NLR;
    const long sO = (long)MR * KHC;
    int b = blockIdx.y;
    int i = blockIdx.x;
    const unsigned short* xl = XLR + (long)b * sX;
    const unsigned short* xr = xl + 1216;
    unsigned short* out = OUT + (long)b * sO;
    int lane = threadIdx.x & 63;
    int h = threadIdx.x >> 6;

    float xr_reg[5], att_reg[5];
#pragma unroll
    for (int q = 0; q < 5; ++q) {
        int c = lane + q * 64;
        if (c < C) {
            xr_reg[q] = b2f(xr[(long)i * NLR + h * C + c]);
            att_reg[q] = att[h * C + c];
        } else { xr_reg[q] = 0.f; att_reg[q] = 0.f; }
    }
    int dg = deg[b * MAXM + i];
    int o0 = off[b * (MAXM + 1) + i];
    const int* cs = csr + b * E;

    float mx = -3e38f, den = 0.f;
    float acc[5] = {0.f, 0.f, 0.f, 0.f, 0.f};
    auto step = [&](int s) {
        const unsigned short* xls = xl + (long)s * NLR + h * C;
        float part = 0.f;
        float xlv[5];
#pragma unroll
        for (int q = 0; q < 5; ++q) {
            int c = lane + q * 64;
            if (c < C) {
                float xv = b2f(xls[c]);
                xlv[q] = xv;
                float v = xv + xr_reg[q];
                v = v > 0.f ? v : NEG * v;
                part += att_reg[q] * v;
            } else xlv[q] = 0.f;
        }
#pragma unroll
        for (int m = 1; m < 64; m <<= 1) part += __shfl_xor(part, m);
        float mn = fmaxf(mx, part);
        float sc = __expf(mx - mn);
        float p = __expf(part - mn);
        den = den * sc + p;
#pragma unroll
        for (int q = 0; q < 5; ++q) acc[q] = acc[q] * sc + p * xlv[q];
        mx = mn;
    };
    step(i);
    for (int e = 0; e < dg; ++e) step(cs[o0 + e]);

    float inv = 1.f / den;
#pragma unroll
    for (int q = 0; q < 5; ++q) {
        int c = lane + q * 64;
        if (c < C) {
            float v = acc[q] * inv + bias[h * C + c];
            out[(long)i * KHC + h * C + c] = f2b(v > 0.f ? v : 0.f);
        }
    }
    if (h == 0 && lane < KHC - HC)
        out[(long)i * KHC + HC + lane] = 0;
}

// ---------------- final A gather: concat(w[h],w[r],w[t]) bf16 padded ----------------
__global__ void k_fgather(const unsigned short* __restrict__ wb, const int* __restrict__ tric,
                          unsigned short* __restrict__ Af) {
    int b = blockIdx.y, t = blockIdx.x;
    const int* tr = tric + ((long)b * T + t) * 3;
    const unsigned short* w = wb + (long)b * (long)MR * WB_LD;
    unsigned short* o = Af + ((long)b * FRW + t) * KF;
    for (int c = threadIdx.x; c < KF; c += 256) {
        if (c < 900) {
            int part = c / 300, kc = c - part * 300;
            o[c] = w[(long)tr[part] * WB_LD + kc];
        } else o[c] = 0;
    }
}

extern "C" void kernel_launch(void* const* d_in, const int* in_sizes, int n_in,
                              void* d_out, int out_size, void* d_ws, size_t ws_size,
                              hipStream_t stream) {
    const int*   kg    = (const int*)d_in[0];
    const float* emb   = (const float*)d_in[1];
    const float* Wl1   = (const float*)d_in[2];
    const float* bl1   = (const float*)d_in[3];
    const float* Wr1   = (const float*)d_in[4];
    const float* br1   = (const float*)d_in[5];
    const float* att1  = (const float*)d_in[6];
    const float* bias1 = (const float*)d_in[7];
    const float* Wl2   = (const float*)d_in[8];
    const float* bl2   = (const float*)d_in[9];
    const float* Wr2   = (const float*)d_in[10];
    const float* br2   = (const float*)d_in[11];
    const float* att2  = (const float*)d_in[12];
    const float* bias2 = (const float*)d_in[13];
    const float* Wp1   = (const float*)d_in[14];
    const float* bp1   = (const float*)d_in[15];
    const float* Wp2   = (const float*)d_in[16];
    const float* bp2   = (const float*)d_in[17];
    const float* Wlii  = (const float*)d_in[18];
    float* out = (float*)d_out;

    char* ws = (char*)d_ws;
    size_t o = 0;
    auto alloc = [&](size_t bytes) -> void* {
        void* p = ws + o;
        o = (o + bytes + 255) & ~(size_t)255;
        return p;
    };
    int* map  = (int*)alloc(sizeof(int) * B * V);
    int* list = (int*)alloc(sizeof(int) * B * MAXM);
    int* mcnt = (int*)alloc(sizeof(int) * B);
    int* deg  = (int*)alloc(sizeof(int) * B * MAXM);
    int* off  = (int*)alloc(sizeof(int) * B * (MAXM + 1));
    int* fill = (int*)alloc(sizeof(int) * B * MAXM);
    int* esrc = (int*)alloc(sizeof(int) * B * E);
    int* edst = (int*)alloc(sizeof(int) * B * E);
    int* csr  = (int*)alloc(sizeof(int) * B * E);
    int* tric = (int*)alloc(sizeof(int) * B * T * 3);

    long sXlr = (long)MR * NLR;
    long sHb  = (long)MR * KHC;
    long sEb  = (long)MR * KD;
    unsigned short* Xlr = (unsigned short*)alloc(2LL * B * sXlr);   // also aliased as Af
    unsigned short* Hb  = (unsigned short*)alloc(2LL * B * sHb);    // also aliased as wb
    unsigned short* Eb  = (unsigned short*)alloc(2LL * B * sEb);    // also aliased as T1b

    unsigned short* Wlr1t = (unsigned short*)alloc(2LL * 2432 * KD);
    unsigned short* Wlr2t = (unsigned short*)alloc(2LL * 2432 * KHC);
    unsigned short* Wp1t  = (unsigned short*)alloc(2LL * 384 * KHC);
    unsigned short* Wp2t  = (unsigned short*)alloc(2LL * 384 * KD);
    unsigned short* Wft   = (unsigned short*)alloc(2LL * 768 * KF);
    float* blr1 = (float*)alloc(sizeof(float) * NLR);
    float* blr2 = (float*)alloc(sizeof(float) * NLR);
    (void)ws_size; (void)in_sizes; (void)n_in; (void)out_size;

    unsigned short* T1b = Eb;    // [B][MR][KD]   (Eb dead after layer-1 GEMM)
    unsigned short* wb  = Hb;    // [B][MR][WB_LD] (Hb dead after proj1)
    unsigned short* Af  = Xlr;   // [B][FRW][KF]   (Xlr dead after att2)

    // graph
    k_init<<<(B * V + 255) / 256, 256, 0, stream>>>(map, list, deg, fill, mcnt);
    k_mark<<<(B * T * 3 + 255) / 256, 256, 0, stream>>>(kg, map);
    k_compact<<<dim3((V + 255) / 256, B), 256, 0, stream>>>(map, list, mcnt);
    k_edges<<<(B * T + 255) / 256, 256, 0, stream>>>(kg, map, esrc, edst, deg, tric);
    k_scan<<<B, 256, 0, stream>>>(deg, off);
    k_scatter<<<(B * E + 255) / 256, 256, 0, stream>>>(esrc, edst, off, fill, csr);

    // weights -> bf16 transposed + combined biases (fused)
    k_wt_all<<<4930, dim3(32, 8), 0, stream>>>(Wl1, Wr1, Wl2, Wr2, Wp1, Wp2, Wlii,
                                               bl1, br1, bl2, br2,
                                               Wlr1t, Wlr2t, Wp1t, Wp2t, Wft, blr1, blr2);

    // embedding gather
    k_embgather<<<dim3(MAXM, B), 128, 0, stream>>>(emb, list, Eb);

    long sWb = (long)MR * WB_LD;
    long sAf = (long)FRW * KF;

    dim3 gL(19, 19, B);   // N=2432 -> 19 tiles, M=2432 -> 19 tiles
    // layer 1 (combined Wl|Wr)
    k_mgemm<<<gL, 256, 0, stream>>>(Eb, sEb, KD, Wlr1t, KD, blr1, MAXM, NLR, KD,
                                    nullptr, 0, 0, Xlr, sXlr, NLR);
    k_att<<<dim3(MAXM, B), 256, 0, stream>>>(Xlr, deg, off, csr, att1, bias1, Hb);
    // layer 2 (combined)
    k_mgemm<<<gL, 256, 0, stream>>>(Hb, sHb, KHC, Wlr2t, KHC, blr2, MAXM, NLR, KHC,
                                    nullptr, 0, 0, Xlr, sXlr, NLR);
    k_att<<<dim3(MAXM, B), 256, 0, stream>>>(Xlr, deg, off, csr, att2, bias2, Hb);
    // projections
    dim3 gP(3, 19, B);
    k_mgemm<<<gP, 256, 0, stream>>>(Hb, sHb, KHC, Wp1t, KHC, bp1, MAXM, C, KHC,
                                    nullptr, 0, 0, T1b, sEb, KD);
    k_mgemm<<<gP, 256, 0, stream>>>(T1b, sEb, KD, Wp2t, KD, bp2, MAXM, C, KD,
                                    nullptr, 0, 0, wb, sWb, WB_LD);
    // final
    k_fgather<<<dim3(T, B), 256, 0, stream>>>(wb, tric, Af);
    k_mgemm<<<dim3(6, 7, B), 256, 0, stream>>>(Af, sAf, KF, Wft, KF, nullptr, T, 768, KF,
                                               out, (long)T * 768, 768, nullptr, 0, 0);
}

// Round 5
// 346.440 us; speedup vs baseline: 5.3061x; 1.0097x over previous
//
#include <hip/hip_runtime.h>
#include <hip/hip_bf16.h>

#define V 30000
#define D 300
#define H 4
#define C 300
#define HC 1200
#define B 2
#define T 800
#define E 1600          // real edges per sample
#define MAXM 2400       // max unique nodes per sample
#define NEG 0.2f
#define SCAN_CH ((MAXM + 255) / 256)

#define MR 2432         // node rows padded to 128-multiple (19*128)
#define KD 320          // D padded to 32-multiple
#define KHC 1216        // HC padded to 32-multiple
#define NLR 2432        // combined Wl|Wr output cols: [0,1200) xl, [1216,2416) xr
#define WB_LD 320       // w bf16 leading dim (300 -> 320 so 8-chunks never straddle parts)
#define KF2 960         // final K: 3 parts x 320
#define FRW 896         // T rows padded (7*128)

typedef __attribute__((ext_vector_type(8))) unsigned short u16x8;
typedef __attribute__((ext_vector_type(8))) short s16x8;
typedef __attribute__((ext_vector_type(4))) float f32x4;

__device__ inline unsigned short f2b(float v) {
    unsigned u = __float_as_uint(v);
    unsigned r = (u + 0x7FFFu + ((u >> 16) & 1u)) >> 16;
    return (unsigned short)r;
}
__device__ inline float b2f(unsigned short u) {
    return __uint_as_float(((unsigned)u) << 16);
}

// async global->LDS, 16B per lane (dest linear in tid per wave; SOURCE is per-lane)
#define GLOAD_LDS16(g, l) __builtin_amdgcn_global_load_lds( \
    (const __attribute__((address_space(1))) void*)(g), \
    (__attribute__((address_space(3))) void*)(l), 16, 0, 0)

// ---------------- graph build ----------------

__global__ void k_init(int* map, int* list, int* deg, int* fill, int* mcnt) {
    int i = blockIdx.x * blockDim.x + threadIdx.x;
    if (i < B * V) map[i] = -1;
    if (i < B * MAXM) { list[i] = 0; deg[i] = 0; fill[i] = 0; }
    if (i < B) mcnt[i] = 0;
}

__global__ void k_mark(const int* __restrict__ kg, int* map) {
    int i = blockIdx.x * blockDim.x + threadIdx.x;
    if (i >= B * T * 3) return;
    int b = i / (T * 3);
    map[b * V + kg[i]] = 1;
}

// ballot-aggregated compaction: one atomic per block (Guideline 12)
__global__ void k_compact(int* map, int* list, int* mcnt) {
    int b = blockIdx.y;
    int i = blockIdx.x * 256 + threadIdx.x;
    bool pred = (i < V) && (map[b * V + i] == 1);
    unsigned long long m = __ballot(pred);
    int lane = threadIdx.x & 63;
    int wid = threadIdx.x >> 6;
    __shared__ int wcnt[4];
    __shared__ int base;
    if (lane == 0) wcnt[wid] = __popcll(m);
    __syncthreads();
    if (threadIdx.x == 0) {
        int t = 0;
#pragma unroll
        for (int w2 = 0; w2 < 4; ++w2) { int c = wcnt[w2]; wcnt[w2] = t; t += c; }
        base = t ? atomicAdd(&mcnt[b], t) : 0;
    }
    __syncthreads();
    if (pred) {
        int idx = base + wcnt[wid] + __popcll(m & ((1ull << lane) - 1ull));
        map[b * V + i] = idx;
        list[b * MAXM + idx] = i;
    }
}

__global__ void k_edges(const int* __restrict__ kg, const int* __restrict__ map,
                        int* esrc, int* edst, int* deg, int* tric) {
    int i = blockIdx.x * blockDim.x + threadIdx.x;
    if (i >= B * T) return;
    int b = i / T, t = i % T;
    const int* kk = kg + ((long)b * T + t) * 3;
    int hc = map[b * V + kk[0]];
    int rc = map[b * V + kk[1]];
    int tc = map[b * V + kk[2]];
    int eb = b * E;
    esrc[eb + t]     = hc;  edst[eb + t]     = rc;
    esrc[eb + T + t] = rc;  edst[eb + T + t] = tc;
    atomicAdd(&deg[b * MAXM + rc], 1);
    atomicAdd(&deg[b * MAXM + tc], 1);
    int* tr = tric + ((long)b * T + t) * 3;
    tr[0] = hc; tr[1] = rc; tr[2] = tc;
}

__global__ void k_scan(const int* __restrict__ deg, int* __restrict__ off) {
    int b = blockIdx.x;
    deg += b * MAXM; off += b * (MAXM + 1);
    __shared__ int ts[256];
    int t = threadIdx.x;
    int base = t * SCAN_CH;
    int loc[SCAN_CH];
    int sum = 0;
#pragma unroll
    for (int j = 0; j < SCAN_CH; ++j) {
        int v = (base + j < MAXM) ? deg[base + j] : 0;
        sum += v; loc[j] = sum;
    }
    ts[t] = sum; __syncthreads();
    for (int s = 1; s < 256; s <<= 1) {
        int v = (t >= s) ? ts[t - s] : 0;
        __syncthreads();
        ts[t] += v;
        __syncthreads();
    }
    int excl = (t > 0) ? ts[t - 1] : 0;
#pragma unroll
    for (int j = 0; j < SCAN_CH; ++j)
        if (base + j < MAXM) off[base + j + 1] = excl + loc[j];
    if (t == 0) off[0] = 0;
}

__global__ void k_scatter(const int* __restrict__ esrc, const int* __restrict__ edst,
                          const int* __restrict__ off, int* fill, int* csr) {
    int i = blockIdx.x * blockDim.x + threadIdx.x;
    if (i >= B * E) return;
    int b = i / E;
    int d = edst[i];
    int pos = off[b * (MAXM + 1) + d] + atomicAdd(&fill[b * MAXM + d], 1);
    csr[b * E + pos] = esrc[i];
}

// ---------------- fused weight prep ----------------
__global__ void k_wt_all(const float* __restrict__ Wl1, const float* __restrict__ Wr1,
                         const float* __restrict__ Wl2, const float* __restrict__ Wr2,
                         const float* __restrict__ Wp1, const float* __restrict__ Wp2,
                         const float* __restrict__ Wlii,
                         const float* __restrict__ bl1, const float* __restrict__ br1,
                         const float* __restrict__ bl2, const float* __restrict__ br2,
                         const float* __restrict__ bp1, const float* __restrict__ bp2,
                         unsigned short* Wlr1t, unsigned short* Wlr2t,
                         unsigned short* Wp2t, unsigned short* Wp1b,
                         unsigned short* Wft2,
                         float* blr1, float* blr2, float* bp12) {
    const int KT[6]  = {10, 10, 38, 38, 10, 30};
    const int CUM[10] = {0, 380, 760, 2204, 3648, 3748, 4468, 4508, 4518, 4520};
    int bid = blockIdx.x;
    int task = 0;
    while (bid >= CUM[task + 1]) ++task;
    int local = bid - CUM[task];
    int tx = threadIdx.x, ty = threadIdx.y;
    int tid = ty * 32 + tx;

    if (task == 6) {   // Wp1b copy: bf16 [1280][320] row-major, zero-padded
        int r0 = local * 32;
#pragma unroll
        for (int p = 0; p < 4; ++p) {
            int row = r0 + ty + p * 8;
#pragma unroll
            for (int j = 0; j < 10; ++j) {
                int c = tx + j * 32;
                unsigned short v = 0;
                if (row < 1200 && c < 300) v = f2b(Wp1[(long)row * 300 + c]);
                Wp1b[(long)row * 320 + c] = v;
            }
        }
        return;
    }
    if (task == 7) {   // combined biases
        int c = local * 256 + tid;
        if (c < NLR) {
            float v1 = 0.f, v2 = 0.f;
            if (c < 1200) { v1 = bl1[c]; v2 = bl2[c]; }
            else if (c >= 1216 && c < 2416) { v1 = br1[c - 1216]; v2 = br2[c - 1216]; }
            blr1[c] = v1; blr2[c] = v2;
        }
        return;
    }
    if (task == 8) {   // bp12 = bp1 @ Wp2 + bp2
        int n = local * 256 + tid;
        if (n < 300) {
            float s = bp2[n];
            for (int m = 0; m < 300; ++m) s += bp1[m] * Wp2[(long)m * 300 + n];
            bp12[n] = s;
        }
        return;
    }

    __shared__ float t[32][33];
    if (task == 5) {   // Wlii -> Wft2[768][960] (part-320 k layout)
        int kt = local % 30, nt = local / 30;
        int k0 = kt * 32, n0 = nt * 32;
#pragma unroll
        for (int p = 0; p < 4; ++p) {
            int gk = k0 + ty + p * 8, n = n0 + tx;
            int pp = (gk >= 640) ? 2 : (gk >= 320 ? 1 : 0);
            int kc = gk - pp * 320;
            t[ty + p * 8][tx] = (kc < 300) ? Wlii[(long)(300 * pp + kc) * 768 + n] : 0.f;
        }
        __syncthreads();
#pragma unroll
        for (int p = 0; p < 4; ++p) {
            int n = n0 + ty + p * 8, gk = k0 + tx;
            Wft2[(long)n * 960 + gk] = f2b(t[tx][ty + p * 8]);
        }
        return;
    }

    int kt = local % KT[task], nt = local / KT[task];
    const float* W; unsigned short* Wt; int K, N, Kp;
    switch (task) {
        case 0: W = Wl1;  Wt = Wlr1t;                     K = 300;  N = 1200; Kp = KD;  break;
        case 1: W = Wr1;  Wt = Wlr1t + (long)1216 * KD;   K = 300;  N = 1200; Kp = KD;  break;
        case 2: W = Wl2;  Wt = Wlr2t;                     K = 1200; N = 1200; Kp = KHC; break;
        case 3: W = Wr2;  Wt = Wlr2t + (long)1216 * KHC;  K = 1200; N = 1200; Kp = KHC; break;
        default: W = Wp2; Wt = Wp2t;                      K = 300;  N = 300;  Kp = KD;  break;
    }
    int k0 = kt * 32, n0 = nt * 32;
#pragma unroll
    for (int p = 0; p < 4; ++p) {
        int k = k0 + ty + p * 8, n = n0 + tx;
        t[ty + p * 8][tx] = (k < K && n < N) ? W[(long)k * N + n] : 0.f;
    }
    __syncthreads();
#pragma unroll
    for (int p = 0; p < 4; ++p) {
        int n = n0 + ty + p * 8, k = k0 + tx;
        Wt[(long)n * Kp + k] = f2b(t[tx][ty + p * 8]);
    }
}

// ---------------- embedding gather f32 -> bf16 padded (vectorized, G13) ----------------
__global__ void k_embgather(const float* __restrict__ emb, const int* __restrict__ list,
                            unsigned short* __restrict__ Eb) {
    int b = blockIdx.y, i = blockIdx.x;
    int src = list[b * MAXM + i];
    const float* e = emb + (long)src * D;
    unsigned short* o = Eb + ((long)b * MR + i) * KD;
    int c = threadIdx.x;
    if (c < 75) {
        float4 v = *(const float4*)(e + c * 4);
        ushort4 u;
        u.x = f2b(v.x); u.y = f2b(v.y); u.z = f2b(v.z); u.w = f2b(v.w);
        *(ushort4*)(o + c * 4) = u;
    } else if (c < 80) {
        *(ushort4*)(o + c * 4) = make_ushort4(0, 0, 0, 0);
    }
}

// ---------------- block-swizzle decode (bijective XCD chunking + group-M) ----------------
__device__ inline void tile_decode(int& m0, int& n0) {
    int nbx = gridDim.x, nby = gridDim.y;
    int nwg = nbx * nby;
    int wg = blockIdx.y * nbx + blockIdx.x;
    int q = nwg >> 3, r8 = nwg & 7;
    int xcd = wg & 7, idx = wg >> 3;
    int L = (xcd < r8 ? xcd * (q + 1) : r8 * (q + 1) + (xcd - r8) * q) + idx;
    const int G = 4;
    int band = L / (G * nbx);
    int first = band * G;
    int sz = min(G, nby - first);
    int rem = L - band * G * nbx;
    int by = first + rem % sz;
    int bx = rem / sz;
    m0 = by * 128; n0 = bx * 128;
}

// ---------------- bf16 MFMA GEMM (global_load_lds + XOR-swizzled LDS) ----------------
__global__ __launch_bounds__(256) void k_mgemm(
    const unsigned short* __restrict__ A, long sA, int lda,
    const unsigned short* __restrict__ Wt, int ldw,
    const float* __restrict__ bias,
    int M, int N, int K,
    float* __restrict__ outF, long sF, int ldf,
    unsigned short* __restrict__ outB, long sB, int ldb_) {
    int b = blockIdx.z;
    A += (long)b * sA;
    __shared__ unsigned short As[128][32];
    __shared__ unsigned short Bs[128][32];
    int tid = threadIdx.x;
    int m0, n0; tile_decode(m0, n0);

    int w = tid >> 6, lane = tid & 63;
    int wr = (w >> 1) * 64, wc = (w & 1) * 64;
    int fr = lane & 15, fq = lane >> 4;
    int r0 = tid >> 2, sg = tid & 3;
    int swz = (sg ^ ((r0 >> 1) & 3)) * 8;   // pre-swizzled global chunk (involution)
    const unsigned short* Ap  = A  + (long)(m0 + r0) * lda + swz;
    const unsigned short* Ap2 = A  + (long)(m0 + r0 + 64) * lda + swz;
    const unsigned short* Bp  = Wt + (long)(n0 + r0) * ldw + swz;
    const unsigned short* Bp2 = Wt + (long)(n0 + r0 + 64) * ldw + swz;
    unsigned short* lA  = &As[r0][sg * 8];
    unsigned short* lA2 = &As[r0 + 64][sg * 8];
    unsigned short* lB  = &Bs[r0][sg * 8];
    unsigned short* lB2 = &Bs[r0 + 64][sg * 8];

    f32x4 acc[4][4] = {};
    for (int k0 = 0; k0 < K; k0 += 32) {
        GLOAD_LDS16(Ap + k0, lA);
        GLOAD_LDS16(Ap2 + k0, lA2);
        GLOAD_LDS16(Bp + k0, lB);
        GLOAD_LDS16(Bp2 + k0, lB2);
        __syncthreads();
        s16x8 af[4], bfr[4];
#pragma unroll
        for (int m = 0; m < 4; ++m) {
            int rr = wr + m * 16 + fr;
            af[m] = *(const s16x8*)&As[rr][(fq ^ ((rr >> 1) & 3)) * 8];
        }
#pragma unroll
        for (int n = 0; n < 4; ++n) {
            int rr = wc + n * 16 + fr;
            bfr[n] = *(const s16x8*)&Bs[rr][(fq ^ ((rr >> 1) & 3)) * 8];
        }
#pragma unroll
        for (int m = 0; m < 4; ++m)
#pragma unroll
            for (int n = 0; n < 4; ++n)
                acc[m][n] = __builtin_amdgcn_mfma_f32_16x16x32_bf16(af[m], bfr[n], acc[m][n], 0, 0, 0);
        __syncthreads();
    }
    float* oF = outF ? outF + (long)b * sF : nullptr;
    unsigned short* oB = outB ? outB + (long)b * sB : nullptr;
#pragma unroll
    for (int m = 0; m < 4; ++m) {
        int rb = m0 + wr + m * 16 + fq * 4;
#pragma unroll
        for (int n = 0; n < 4; ++n) {
            int col = n0 + wc + n * 16 + fr;
#pragma unroll
            for (int j = 0; j < 4; ++j) {
                int row = rb + j;
                if (row >= M) continue;
                if (col < N) {
                    float v = acc[m][n][j] + (bias ? bias[col] : 0.f);
                    if (oF) oF[(long)row * ldf + col] = v;
                    if (oB) oB[(long)row * ldb_ + col] = f2b(v);
                } else if (oB && col < ldb_) {
                    oB[(long)row * ldb_ + col] = 0;
                }
            }
        }
    }
}

// ---------------- final GEMM with fused tric-gather A ----------------
__global__ __launch_bounds__(256) void k_fgemm(
    const unsigned short* __restrict__ wb, long sW,
    const int* __restrict__ tric,
    const unsigned short* __restrict__ Wft2,
    float* __restrict__ out) {
    int b = blockIdx.z;
    const unsigned short* wB = wb + (long)b * sW;
    const int* tr = tric + (long)b * T * 3;
    float* oF = out + (long)b * T * 768;
    __shared__ unsigned short As[128][32];
    __shared__ unsigned short Bs[128][32];
    int tid = threadIdx.x;
    int m0, n0; tile_decode(m0, n0);

    int w = tid >> 6, lane = tid & 63;
    int wr = (w >> 1) * 64, wc = (w & 1) * 64;
    int fr = lane & 15, fq = lane >> 4;
    int r0 = tid >> 2, sg = tid & 3;
    int swz = (sg ^ ((r0 >> 1) & 3)) * 8;

    int gm  = m0 + r0;
    int gm2 = gm + 64;
    int t1 = min(gm, T - 1) * 3, t2 = min(gm2, T - 1) * 3;
    int tr0a = tr[t1], tr1a = tr[t1 + 1], tr2a = tr[t1 + 2];
    int tr0b = tr[t2], tr1b = tr[t2 + 1], tr2b = tr[t2 + 2];

    const unsigned short* Bp  = Wft2 + (long)(n0 + r0) * KF2 + swz;
    const unsigned short* Bp2 = Wft2 + (long)(n0 + r0 + 64) * KF2 + swz;
    unsigned short* lA  = &As[r0][sg * 8];
    unsigned short* lA2 = &As[r0 + 64][sg * 8];
    unsigned short* lB  = &Bs[r0][sg * 8];
    unsigned short* lB2 = &Bs[r0 + 64][sg * 8];

    f32x4 acc[4][4] = {};
    for (int k0 = 0; k0 < KF2; k0 += 32) {
        int kk = k0 + swz;
        int p_ = (kk >= 640) ? 2 : (kk >= 320 ? 1 : 0);
        int kc = kk - p_ * 320;
        int tA  = (p_ == 0) ? tr0a : (p_ == 1 ? tr1a : tr2a);
        int tA2 = (p_ == 0) ? tr0b : (p_ == 1 ? tr1b : tr2b);
        GLOAD_LDS16(wB + (long)tA * WB_LD + kc, lA);
        GLOAD_LDS16(wB + (long)tA2 * WB_LD + kc, lA2);
        GLOAD_LDS16(Bp + k0, lB);
        GLOAD_LDS16(Bp2 + k0, lB2);
        __syncthreads();
        s16x8 af[4], bfr[4];
#pragma unroll
        for (int m = 0; m < 4; ++m) {
            int rr = wr + m * 16 + fr;
            af[m] = *(const s16x8*)&As[rr][(fq ^ ((rr >> 1) & 3)) * 8];
        }
#pragma unroll
        for (int n = 0; n < 4; ++n) {
            int rr = wc + n * 16 + fr;
            bfr[n] = *(const s16x8*)&Bs[rr][(fq ^ ((rr >> 1) & 3)) * 8];
        }
#pragma unroll
        for (int m = 0; m < 4; ++m)
#pragma unroll
            for (int n = 0; n < 4; ++n)
                acc[m][n] = __builtin_amdgcn_mfma_f32_16x16x32_bf16(af[m], bfr[n], acc[m][n], 0, 0, 0);
        __syncthreads();
    }
#pragma unroll
    for (int m = 0; m < 4; ++m) {
        int rb = m0 + wr + m * 16 + fq * 4;
#pragma unroll
        for (int n = 0; n < 4; ++n) {
            int col = n0 + wc + n * 16 + fr;
#pragma unroll
            for (int j = 0; j < 4; ++j) {
                int row = rb + j;
                if (row < T) oF[(long)row * 768 + col] = acc[m][n][j];
            }
        }
    }
}

// ---------------- GATv2 attention: single-pass online softmax, vectorized IO ----------------
__global__ __launch_bounds__(256) void k_att(
    const unsigned short* __restrict__ XLR,
    const int* __restrict__ deg, const int* __restrict__ off, const int* __restrict__ csr,
    const float* __restrict__ att, const float* __restrict__ bias,
    unsigned short* __restrict__ OUT) {
    const long sX = (long)MR * NLR;
    const long sO = (long)MR * KHC;
    int b = blockIdx.y;
    int i = blockIdx.x;
    const unsigned short* xl = XLR + (long)b * sX;
    const unsigned short* xr = xl + 1216;
    unsigned short* out = OUT + (long)b * sO;
    int lane = threadIdx.x & 63;
    int h = threadIdx.x >> 6;
    int c0 = lane * 4;
    int c1 = 256 + c0;
    bool tail = lane < 11;

    float xrf[8], attf[8];
    {
        const unsigned short* xp = xr + (long)i * NLR + h * C;
        ushort4 u0 = *(const ushort4*)(xp + c0);
        ushort4 u1 = tail ? *(const ushort4*)(xp + c1) : make_ushort4(0, 0, 0, 0);
        xrf[0] = b2f(u0.x); xrf[1] = b2f(u0.y); xrf[2] = b2f(u0.z); xrf[3] = b2f(u0.w);
        xrf[4] = b2f(u1.x); xrf[5] = b2f(u1.y); xrf[6] = b2f(u1.z); xrf[7] = b2f(u1.w);
        float4 a0 = *(const float4*)(att + h * C + c0);
        attf[0] = a0.x; attf[1] = a0.y; attf[2] = a0.z; attf[3] = a0.w;
        if (tail) {
            float4 a1 = *(const float4*)(att + h * C + c1);
            attf[4] = a1.x; attf[5] = a1.y; attf[6] = a1.z; attf[7] = a1.w;
        } else { attf[4] = attf[5] = attf[6] = attf[7] = 0.f; }
    }
    int dg = deg[b * MAXM + i];
    int o0 = off[b * (MAXM + 1) + i];
    const int* cs = csr + b * E;

    float mx = -3e38f, den = 0.f;
    float acc[8] = {0.f, 0.f, 0.f, 0.f, 0.f, 0.f, 0.f, 0.f};
    auto step = [&](int s) {
        const unsigned short* xp = xl + (long)s * NLR + h * C;
        ushort4 v0 = *(const ushort4*)(xp + c0);
        ushort4 v1 = tail ? *(const ushort4*)(xp + c1) : make_ushort4(0, 0, 0, 0);
        float xv[8];
        xv[0] = b2f(v0.x); xv[1] = b2f(v0.y); xv[2] = b2f(v0.z); xv[3] = b2f(v0.w);
        xv[4] = b2f(v1.x); xv[5] = b2f(v1.y); xv[6] = b2f(v1.z); xv[7] = b2f(v1.w);
        float part = 0.f;
#pragma unroll
        for (int j = 0; j < 8; ++j) {
            float v = xv[j] + xrf[j];
            v = v > 0.f ? v : NEG * v;
            part += attf[j] * v;
        }
#pragma unroll
        for (int m = 1; m < 64; m <<= 1) part += __shfl_xor(part, m);
        float mn = fmaxf(mx, part);
        float sc = __expf(mx - mn);
        float p = __expf(part - mn);
        den = den * sc + p;
#pragma unroll
        for (int j = 0; j < 8; ++j) acc[j] = acc[j] * sc + p * xv[j];
        mx = mn;
    };
    step(i);
    for (int e = 0; e < dg; ++e) step(cs[o0 + e]);

    float inv = 1.f / den;
    unsigned short* op = out + (long)i * KHC + h * C;
    {
        float4 b0 = *(const float4*)(bias + h * C + c0);
        ushort4 s0;
        float v;
        v = acc[0] * inv + b0.x; s0.x = f2b(v > 0.f ? v : 0.f);
        v = acc[1] * inv + b0.y; s0.y = f2b(v > 0.f ? v : 0.f);
        v = acc[2] * inv + b0.z; s0.z = f2b(v > 0.f ? v : 0.f);
        v = acc[3] * inv + b0.w; s0.w = f2b(v > 0.f ? v : 0.f);
        *(ushort4*)(op + c0) = s0;
        if (tail) {
            float4 b1 = *(const float4*)(bias + h * C + c1);
            ushort4 s1;
            v = acc[4] * inv + b1.x; s1.x = f2b(v > 0.f ? v : 0.f);
            v = acc[5] * inv + b1.y; s1.y = f2b(v > 0.f ? v : 0.f);
            v = acc[6] * inv + b1.z; s1.z = f2b(v > 0.f ? v : 0.f);
            v = acc[7] * inv + b1.w; s1.w = f2b(v > 0.f ? v : 0.f);
            *(ushort4*)(op + c1) = s1;
        }
    }
    if (h == 0 && lane < KHC - HC)
        out[(long)i * KHC + HC + lane] = 0;
}

extern "C" void kernel_launch(void* const* d_in, const int* in_sizes, int n_in,
                              void* d_out, int out_size, void* d_ws, size_t ws_size,
                              hipStream_t stream) {
    const int*   kg    = (const int*)d_in[0];
    const float* emb   = (const float*)d_in[1];
    const float* Wl1   = (const float*)d_in[2];
    const float* bl1   = (const float*)d_in[3];
    const float* Wr1   = (const float*)d_in[4];
    const float* br1   = (const float*)d_in[5];
    const float* att1  = (const float*)d_in[6];
    const float* bias1 = (const float*)d_in[7];
    const float* Wl2   = (const float*)d_in[8];
    const float* bl2   = (const float*)d_in[9];
    const float* Wr2   = (const float*)d_in[10];
    const float* br2   = (const float*)d_in[11];
    const float* att2  = (const float*)d_in[12];
    const float* bias2 = (const float*)d_in[13];
    const float* Wp1   = (const float*)d_in[14];
    const float* bp1   = (const float*)d_in[15];
    const float* Wp2   = (const float*)d_in[16];
    const float* bp2   = (const float*)d_in[17];
    const float* Wlii  = (const float*)d_in[18];
    float* out = (float*)d_out;

    char* ws = (char*)d_ws;
    size_t o = 0;
    auto alloc = [&](size_t bytes) -> void* {
        void* p = ws + o;
        o = (o + bytes + 255) & ~(size_t)255;
        return p;
    };
    int* map  = (int*)alloc(sizeof(int) * B * V);
    int* list = (int*)alloc(sizeof(int) * B * MAXM);
    int* mcnt = (int*)alloc(sizeof(int) * B);
    int* deg  = (int*)alloc(sizeof(int) * B * MAXM);
    int* off  = (int*)alloc(sizeof(int) * B * (MAXM + 1));
    int* fill = (int*)alloc(sizeof(int) * B * MAXM);
    int* esrc = (int*)alloc(sizeof(int) * B * E);
    int* edst = (int*)alloc(sizeof(int) * B * E);
    int* csr  = (int*)alloc(sizeof(int) * B * E);
    int* tric = (int*)alloc(sizeof(int) * B * T * 3);

    long sXlr = (long)MR * NLR;
    long sHb  = (long)MR * KHC;
    long sEb  = (long)MR * KD;
    unsigned short* Xlr = (unsigned short*)alloc(2LL * B * sXlr);
    unsigned short* Hb  = (unsigned short*)alloc(2LL * B * sHb);
    unsigned short* Eb  = (unsigned short*)alloc(2LL * B * sEb);   // aliased as wb after L1 GEMM

    unsigned short* Wlr1t = (unsigned short*)alloc(2LL * 2432 * KD);
    unsigned short* Wlr2t = (unsigned short*)alloc(2LL * 2432 * KHC);
    unsigned short* Wp2t  = (unsigned short*)alloc(2LL * 384 * KD);
    unsigned short* Wp1b  = (unsigned short*)alloc(2LL * 1280 * 320);
    unsigned short* Wp12t = (unsigned short*)alloc(2LL * 384 * KHC);
    unsigned short* Wft2  = (unsigned short*)alloc(2LL * 768 * KF2);
    float* blr1 = (float*)alloc(sizeof(float) * NLR);
    float* blr2 = (float*)alloc(sizeof(float) * NLR);
    float* bp12 = (float*)alloc(sizeof(float) * 384);
    (void)ws_size; (void)in_sizes; (void)n_in; (void)out_size;

    unsigned short* wb = Eb;    // [B][MR][WB_LD=320] (Eb dead after layer-1 GEMM; KD==WB_LD)

    // graph
    k_init<<<(B * V + 255) / 256, 256, 0, stream>>>(map, list, deg, fill, mcnt);
    k_mark<<<(B * T * 3 + 255) / 256, 256, 0, stream>>>(kg, map);
    k_compact<<<dim3((V + 255) / 256, B), 256, 0, stream>>>(map, list, mcnt);
    k_edges<<<(B * T + 255) / 256, 256, 0, stream>>>(kg, map, esrc, edst, deg, tric);
    k_scan<<<B, 256, 0, stream>>>(deg, off);
    k_scatter<<<(B * E + 255) / 256, 256, 0, stream>>>(esrc, edst, off, fill, csr);

    // weight prep
    k_wt_all<<<4520, dim3(32, 8), 0, stream>>>(Wl1, Wr1, Wl2, Wr2, Wp1, Wp2, Wlii,
                                               bl1, br1, bl2, br2, bp1, bp2,
                                               Wlr1t, Wlr2t, Wp2t, Wp1b, Wft2,
                                               blr1, blr2, bp12);

    // embedding gather
    k_embgather<<<dim3(MAXM, B), 128, 0, stream>>>(emb, list, Eb);

    // Wp12t[n][k] = (Wp1 @ Wp2)[k][n]  (bf16 fused projection weight)
    k_mgemm<<<dim3(10, 3, 1), 256, 0, stream>>>(Wp2t, 0, KD, Wp1b, 320, nullptr,
                                                300, 1216, KD,
                                                nullptr, 0, 0, Wp12t, 0, KHC);

    long sWb = (long)MR * WB_LD;

    dim3 gL(19, 19, B);
    // layer 1 (combined Wl|Wr)
    k_mgemm<<<gL, 256, 0, stream>>>(Eb, sEb, KD, Wlr1t, KD, blr1, MAXM, NLR, KD,
                                    nullptr, 0, 0, Xlr, sXlr, NLR);
    k_att<<<dim3(MAXM, B), 256, 0, stream>>>(Xlr, deg, off, csr, att1, bias1, Hb);
    // layer 2 (combined)
    k_mgemm<<<gL, 256, 0, stream>>>(Hb, sHb, KHC, Wlr2t, KHC, blr2, MAXM, NLR, KHC,
                                    nullptr, 0, 0, Xlr, sXlr, NLR);
    k_att<<<dim3(MAXM, B), 256, 0, stream>>>(Xlr, deg, off, csr, att2, bias2, Hb);
    // fused projection: w = h @ Wp12 + bp12  (reads Hb, writes wb=Eb)
    k_mgemm<<<dim3(3, 19, B), 256, 0, stream>>>(Hb, sHb, KHC, Wp12t, KHC, bp12,
                                                MAXM, 300, KHC,
                                                nullptr, 0, 0, wb, sWb, WB_LD);
    // final (fused tric-gather)
    k_fgemm<<<dim3(6, 7, B), 256, 0, stream>>>(wb, sWb, tric, Wft2, out);
}

// Round 6
// 328.517 us; speedup vs baseline: 5.5956x; 1.0546x over previous
//
#include <hip/hip_runtime.h>
#include <hip/hip_bf16.h>

#define V 30000
#define D 300
#define H 4
#define C 300
#define HC 1200
#define B 2
#define T 800
#define E 1600          // real edges per sample
#define MAXM 2400       // max unique nodes per sample
#define NEG 0.2f
#define SCAN_CH ((MAXM + 255) / 256)

#define MR 2432         // node rows padded to 128-multiple (19*128)
#define KD 320          // D padded to 32-multiple
#define KHC 1216        // HC padded to 32-multiple
#define NLR 2432        // combined Wl|Wr output cols: [0,1200) xl, [1216,2416) xr
#define WB_LD 320       // w bf16 leading dim (300 -> 320 so 8-chunks never straddle parts)
#define KF2 960         // final K: 3 parts x 320

typedef __attribute__((ext_vector_type(8))) unsigned short u16x8;
typedef __attribute__((ext_vector_type(8))) short s16x8;
typedef __attribute__((ext_vector_type(4))) float f32x4;

__device__ inline unsigned short f2b(float v) {
    unsigned u = __float_as_uint(v);
    unsigned r = (u + 0x7FFFu + ((u >> 16) & 1u)) >> 16;
    return (unsigned short)r;
}
__device__ inline float b2f(unsigned short u) {
    return __uint_as_float(((unsigned)u) << 16);
}

// async global->LDS, 16B per lane (dest linear in tid per wave; SOURCE is per-lane)
#define GLOAD_LDS16(g, l) __builtin_amdgcn_global_load_lds( \
    (const __attribute__((address_space(1))) void*)(g), \
    (__attribute__((address_space(3))) void*)(l), 16, 0, 0)

// ---------------- graph build ----------------

__global__ void k_init(int* map, int* list, int* mcnt) {
    int i = blockIdx.x * blockDim.x + threadIdx.x;
    if (i < B * V) map[i] = -1;
    if (i < B * MAXM) list[i] = 0;
    if (i < B) mcnt[i] = 0;
}

__global__ void k_mark(const int* __restrict__ kg, int* map) {
    int i = blockIdx.x * blockDim.x + threadIdx.x;
    if (i >= B * T * 3) return;
    int b = i / (T * 3);
    map[b * V + kg[i]] = 1;
}

// ballot-aggregated compaction: one atomic per block (Guideline 12)
__global__ void k_compact(int* map, int* list, int* mcnt) {
    int b = blockIdx.y;
    int i = blockIdx.x * 256 + threadIdx.x;
    bool pred = (i < V) && (map[b * V + i] == 1);
    unsigned long long m = __ballot(pred);
    int lane = threadIdx.x & 63;
    int wid = threadIdx.x >> 6;
    __shared__ int wcnt[4];
    __shared__ int base;
    if (lane == 0) wcnt[wid] = __popcll(m);
    __syncthreads();
    if (threadIdx.x == 0) {
        int t = 0;
#pragma unroll
        for (int w2 = 0; w2 < 4; ++w2) { int c = wcnt[w2]; wcnt[w2] = t; t += c; }
        base = t ? atomicAdd(&mcnt[b], t) : 0;
    }
    __syncthreads();
    if (pred) {
        int idx = base + wcnt[wid] + __popcll(m & ((1ull << lane) - 1ull));
        map[b * V + i] = idx;
        list[b * MAXM + idx] = i;
    }
}

// edges + degree histogram + exclusive scan + CSR scatter, all in LDS, one block/sample
__global__ __launch_bounds__(256) void k_graph(const int* __restrict__ kg,
                                               const int* __restrict__ map,
                                               int* __restrict__ off_g,
                                               int* __restrict__ csr,
                                               int* __restrict__ tric) {
    int b = blockIdx.x;
    int tid = threadIdx.x;
    __shared__ int sdeg[MAXM];
    __shared__ int soff[MAXM + 1];
    __shared__ int ses[E];
    __shared__ int sed[E];
    __shared__ int ts[256];
    for (int j = tid; j < MAXM; j += 256) sdeg[j] = 0;
    __syncthreads();
    for (int t = tid; t < T; t += 256) {
        const int* kk = kg + ((long)b * T + t) * 3;
        int hc = map[b * V + kk[0]];
        int rc = map[b * V + kk[1]];
        int tc = map[b * V + kk[2]];
        ses[t] = hc;     sed[t] = rc;
        ses[T + t] = rc; sed[T + t] = tc;
        atomicAdd(&sdeg[rc], 1);
        atomicAdd(&sdeg[tc], 1);
        int* tr = tric + ((long)b * T + t) * 3;
        tr[0] = hc; tr[1] = rc; tr[2] = tc;
    }
    __syncthreads();
    // exclusive scan sdeg -> soff
    int base = tid * SCAN_CH;
    int loc[SCAN_CH];
    int sum = 0;
#pragma unroll
    for (int j = 0; j < SCAN_CH; ++j) {
        int v = (base + j < MAXM) ? sdeg[base + j] : 0;
        sum += v; loc[j] = sum;
    }
    ts[tid] = sum; __syncthreads();
    for (int s = 1; s < 256; s <<= 1) {
        int v = (tid >= s) ? ts[tid - s] : 0;
        __syncthreads();
        ts[tid] += v;
        __syncthreads();
    }
    int excl = (tid > 0) ? ts[tid - 1] : 0;
#pragma unroll
    for (int j = 0; j < SCAN_CH; ++j)
        if (base + j < MAXM) soff[base + j + 1] = excl + loc[j];
    if (tid == 0) soff[0] = 0;
    __syncthreads();
    // reuse sdeg as fill counters
    for (int j = tid; j < MAXM; j += 256) sdeg[j] = 0;
    __syncthreads();
    for (int e = tid; e < E; e += 256) {
        int d = sed[e];
        int pos = soff[d] + atomicAdd(&sdeg[d], 1);
        csr[b * E + pos] = ses[e];
    }
    for (int j = tid; j <= MAXM; j += 256) off_g[b * (MAXM + 1) + j] = soff[j];
}

// ---------------- fused weight prep ----------------
__global__ void k_wt_all(const float* __restrict__ Wl1, const float* __restrict__ Wr1,
                         const float* __restrict__ Wl2, const float* __restrict__ Wr2,
                         const float* __restrict__ Wp1, const float* __restrict__ Wp2,
                         const float* __restrict__ Wlii,
                         const float* __restrict__ bl1, const float* __restrict__ br1,
                         const float* __restrict__ bl2, const float* __restrict__ br2,
                         const float* __restrict__ bp1, const float* __restrict__ bp2,
                         unsigned short* Wlr1t, unsigned short* Wlr2t,
                         unsigned short* Wp2t, unsigned short* Wp1b,
                         unsigned short* Wft2,
                         float* blr1, float* blr2, float* bp12) {
    const int KT[6]  = {10, 10, 38, 38, 10, 30};
    const int CUM[10] = {0, 380, 760, 2204, 3648, 3748, 4468, 4508, 4518, 4520};
    int bid = blockIdx.x;
    int task = 0;
    while (bid >= CUM[task + 1]) ++task;
    int local = bid - CUM[task];
    int tx = threadIdx.x, ty = threadIdx.y;
    int tid = ty * 32 + tx;

    if (task == 6) {   // Wp1b copy: bf16 [1280][320] row-major, zero-padded
        int r0 = local * 32;
#pragma unroll
        for (int p = 0; p < 4; ++p) {
            int row = r0 + ty + p * 8;
#pragma unroll
            for (int j = 0; j < 10; ++j) {
                int c = tx + j * 32;
                unsigned short v = 0;
                if (row < 1200 && c < 300) v = f2b(Wp1[(long)row * 300 + c]);
                Wp1b[(long)row * 320 + c] = v;
            }
        }
        return;
    }
    if (task == 7) {   // combined biases
        int c = local * 256 + tid;
        if (c < NLR) {
            float v1 = 0.f, v2 = 0.f;
            if (c < 1200) { v1 = bl1[c]; v2 = bl2[c]; }
            else if (c >= 1216 && c < 2416) { v1 = br1[c - 1216]; v2 = br2[c - 1216]; }
            blr1[c] = v1; blr2[c] = v2;
        }
        return;
    }
    if (task == 8) {   // bp12 = bp1 @ Wp2 + bp2
        int n = local * 256 + tid;
        if (n < 300) {
            float s = bp2[n];
            for (int m = 0; m < 300; ++m) s += bp1[m] * Wp2[(long)m * 300 + n];
            bp12[n] = s;
        }
        return;
    }

    __shared__ float t[32][33];
    if (task == 5) {   // Wlii -> Wft2[768][960] (part-320 k layout)
        int kt = local % 30, nt = local / 30;
        int k0 = kt * 32, n0 = nt * 32;
#pragma unroll
        for (int p = 0; p < 4; ++p) {
            int gk = k0 + ty + p * 8, n = n0 + tx;
            int pp = (gk >= 640) ? 2 : (gk >= 320 ? 1 : 0);
            int kc = gk - pp * 320;
            t[ty + p * 8][tx] = (kc < 300) ? Wlii[(long)(300 * pp + kc) * 768 + n] : 0.f;
        }
        __syncthreads();
#pragma unroll
        for (int p = 0; p < 4; ++p) {
            int n = n0 + ty + p * 8, gk = k0 + tx;
            Wft2[(long)n * 960 + gk] = f2b(t[tx][ty + p * 8]);
        }
        return;
    }

    int kt = local % KT[task], nt = local / KT[task];
    const float* W; unsigned short* Wt; int K, N, Kp;
    switch (task) {
        case 0: W = Wl1;  Wt = Wlr1t;                     K = 300;  N = 1200; Kp = KD;  break;
        case 1: W = Wr1;  Wt = Wlr1t + (long)1216 * KD;   K = 300;  N = 1200; Kp = KD;  break;
        case 2: W = Wl2;  Wt = Wlr2t;                     K = 1200; N = 1200; Kp = KHC; break;
        case 3: W = Wr2;  Wt = Wlr2t + (long)1216 * KHC;  K = 1200; N = 1200; Kp = KHC; break;
        default: W = Wp2; Wt = Wp2t;                      K = 300;  N = 300;  Kp = KD;  break;
    }
    int k0 = kt * 32, n0 = nt * 32;
#pragma unroll
    for (int p = 0; p < 4; ++p) {
        int k = k0 + ty + p * 8, n = n0 + tx;
        t[ty + p * 8][tx] = (k < K && n < N) ? W[(long)k * N + n] : 0.f;
    }
    __syncthreads();
#pragma unroll
    for (int p = 0; p < 4; ++p) {
        int n = n0 + ty + p * 8, k = k0 + tx;
        Wt[(long)n * Kp + k] = f2b(t[tx][ty + p * 8]);
    }
}

// ---------------- embedding gather f32 -> bf16 padded (vectorized, G13) ----------------
__global__ void k_embgather(const float* __restrict__ emb, const int* __restrict__ list,
                            unsigned short* __restrict__ Eb) {
    int b = blockIdx.y, i = blockIdx.x;
    int src = list[b * MAXM + i];
    const float* e = emb + (long)src * D;
    unsigned short* o = Eb + ((long)b * MR + i) * KD;
    int c = threadIdx.x;
    if (c < 75) {
        float4 v = *(const float4*)(e + c * 4);
        ushort4 u;
        u.x = f2b(v.x); u.y = f2b(v.y); u.z = f2b(v.z); u.w = f2b(v.w);
        *(ushort4*)(o + c * 4) = u;
    } else if (c < 80) {
        *(ushort4*)(o + c * 4) = make_ushort4(0, 0, 0, 0);
    }
}

// ---------------- block-swizzle decode (bijective XCD chunking + group-M) ----------------
__device__ inline void tile_decode(int& m0, int& n0) {
    int nbx = gridDim.x, nby = gridDim.y;
    int nwg = nbx * nby;
    int wg = blockIdx.y * nbx + blockIdx.x;
    int q = nwg >> 3, r8 = nwg & 7;
    int xcd = wg & 7, idx = wg >> 3;
    int L = (xcd < r8 ? xcd * (q + 1) : r8 * (q + 1) + (xcd - r8) * q) + idx;
    const int G = 4;
    int band = L / (G * nbx);
    int first = band * G;
    int sz = min(G, nby - first);
    int rem = L - band * G * nbx;
    int by = first + rem % sz;
    int bx = rem / sz;
    m0 = by * 128; n0 = bx * 128;
}

// ---------------- bf16 MFMA GEMM (dbuf prefetch + global_load_lds + XOR swizzle) --------
__global__ __launch_bounds__(256) void k_mgemm(
    const unsigned short* __restrict__ A, long sA, int lda,
    const unsigned short* __restrict__ Wt, int ldw,
    const float* __restrict__ bias,
    int M, int N, int K,
    float* __restrict__ outF, long sF, int ldf,
    unsigned short* __restrict__ outB, long sB, int ldb_) {
    int b = blockIdx.z;
    A += (long)b * sA;
    __shared__ unsigned short As[2][128][32];
    __shared__ unsigned short Bs[2][128][32];
    int tid = threadIdx.x;
    int m0, n0; tile_decode(m0, n0);

    int w = tid >> 6, lane = tid & 63;
    int wr = (w >> 1) * 64, wc = (w & 1) * 64;
    int fr = lane & 15, fq = lane >> 4;
    int r0 = tid >> 2, sg = tid & 3;
    int swz = (sg ^ ((r0 >> 1) & 3)) * 8;   // pre-swizzled global chunk (involution)
    const unsigned short* Ap  = A  + (long)(m0 + r0) * lda + swz;
    const unsigned short* Ap2 = A  + (long)(m0 + r0 + 64) * lda + swz;
    const unsigned short* Bp  = Wt + (long)(n0 + r0) * ldw + swz;
    const unsigned short* Bp2 = Wt + (long)(n0 + r0 + 64) * ldw + swz;

    f32x4 acc[4][4] = {};
    // prologue: stage k0=0 into buf 0
    GLOAD_LDS16(Ap,  &As[0][r0][sg * 8]);
    GLOAD_LDS16(Ap2, &As[0][r0 + 64][sg * 8]);
    GLOAD_LDS16(Bp,  &Bs[0][r0][sg * 8]);
    GLOAD_LDS16(Bp2, &Bs[0][r0 + 64][sg * 8]);
    __syncthreads();
    int cur = 0;
    for (int k0 = 0; k0 < K; k0 += 32) {
        int nxt = cur ^ 1;
        if (k0 + 32 < K) {   // prefetch next tile BEFORE compute (T3)
            GLOAD_LDS16(Ap + k0 + 32,  &As[nxt][r0][sg * 8]);
            GLOAD_LDS16(Ap2 + k0 + 32, &As[nxt][r0 + 64][sg * 8]);
            GLOAD_LDS16(Bp + k0 + 32,  &Bs[nxt][r0][sg * 8]);
            GLOAD_LDS16(Bp2 + k0 + 32, &Bs[nxt][r0 + 64][sg * 8]);
        }
        s16x8 af[4], bfr[4];
#pragma unroll
        for (int m = 0; m < 4; ++m) {
            int rr = wr + m * 16 + fr;
            af[m] = *(const s16x8*)&As[cur][rr][(fq ^ ((rr >> 1) & 3)) * 8];
        }
#pragma unroll
        for (int n = 0; n < 4; ++n) {
            int rr = wc + n * 16 + fr;
            bfr[n] = *(const s16x8*)&Bs[cur][rr][(fq ^ ((rr >> 1) & 3)) * 8];
        }
#pragma unroll
        for (int m = 0; m < 4; ++m)
#pragma unroll
            for (int n = 0; n < 4; ++n)
                acc[m][n] = __builtin_amdgcn_mfma_f32_16x16x32_bf16(af[m], bfr[n], acc[m][n], 0, 0, 0);
        __syncthreads();   // drains the prefetch, guards buffer swap
        cur = nxt;
    }
    float* oF = outF ? outF + (long)b * sF : nullptr;
    unsigned short* oB = outB ? outB + (long)b * sB : nullptr;
#pragma unroll
    for (int m = 0; m < 4; ++m) {
        int rb = m0 + wr + m * 16 + fq * 4;
#pragma unroll
        for (int n = 0; n < 4; ++n) {
            int col = n0 + wc + n * 16 + fr;
#pragma unroll
            for (int j = 0; j < 4; ++j) {
                int row = rb + j;
                if (row >= M) continue;
                if (col < N) {
                    float v = acc[m][n][j] + (bias ? bias[col] : 0.f);
                    if (oF) oF[(long)row * ldf + col] = v;
                    if (oB) oB[(long)row * ldb_ + col] = f2b(v);
                } else if (oB && col < ldb_) {
                    oB[(long)row * ldb_ + col] = 0;
                }
            }
        }
    }
}

// ---------------- final GEMM with fused tric-gather A (dbuf prefetch) ----------------
__global__ __launch_bounds__(256) void k_fgemm(
    const unsigned short* __restrict__ wb, long sW,
    const int* __restrict__ tric,
    const unsigned short* __restrict__ Wft2,
    float* __restrict__ out) {
    int b = blockIdx.z;
    const unsigned short* wB = wb + (long)b * sW;
    const int* tr = tric + (long)b * T * 3;
    float* oF = out + (long)b * T * 768;
    __shared__ unsigned short As[2][128][32];
    __shared__ unsigned short Bs[2][128][32];
    int tid = threadIdx.x;
    int m0, n0; tile_decode(m0, n0);

    int w = tid >> 6, lane = tid & 63;
    int wr = (w >> 1) * 64, wc = (w & 1) * 64;
    int fr = lane & 15, fq = lane >> 4;
    int r0 = tid >> 2, sg = tid & 3;
    int swz = (sg ^ ((r0 >> 1) & 3)) * 8;

    int gm  = m0 + r0;
    int gm2 = gm + 64;
    int t1 = min(gm, T - 1) * 3, t2 = min(gm2, T - 1) * 3;
    int tr_a[3] = {tr[t1], tr[t1 + 1], tr[t1 + 2]};
    int tr_b[3] = {tr[t2], tr[t2 + 1], tr[t2 + 2]};

    const unsigned short* Bp  = Wft2 + (long)(n0 + r0) * KF2 + swz;
    const unsigned short* Bp2 = Wft2 + (long)(n0 + r0 + 64) * KF2 + swz;

    auto stage = [&](int buf, int k0) {
        int kk = k0 + swz;
        int p_ = (kk >= 640) ? 2 : (kk >= 320 ? 1 : 0);
        int kc = kk - p_ * 320;
        GLOAD_LDS16(wB + (long)tr_a[p_] * WB_LD + kc, &As[buf][r0][sg * 8]);
        GLOAD_LDS16(wB + (long)tr_b[p_] * WB_LD + kc, &As[buf][r0 + 64][sg * 8]);
        GLOAD_LDS16(Bp + k0,  &Bs[buf][r0][sg * 8]);
        GLOAD_LDS16(Bp2 + k0, &Bs[buf][r0 + 64][sg * 8]);
    };

    f32x4 acc[4][4] = {};
    stage(0, 0);
    __syncthreads();
    int cur = 0;
    for (int k0 = 0; k0 < KF2; k0 += 32) {
        int nxt = cur ^ 1;
        if (k0 + 32 < KF2) stage(nxt, k0 + 32);
        s16x8 af[4], bfr[4];
#pragma unroll
        for (int m = 0; m < 4; ++m) {
            int rr = wr + m * 16 + fr;
            af[m] = *(const s16x8*)&As[cur][rr][(fq ^ ((rr >> 1) & 3)) * 8];
        }
#pragma unroll
        for (int n = 0; n < 4; ++n) {
            int rr = wc + n * 16 + fr;
            bfr[n] = *(const s16x8*)&Bs[cur][rr][(fq ^ ((rr >> 1) & 3)) * 8];
        }
#pragma unroll
        for (int m = 0; m < 4; ++m)
#pragma unroll
            for (int n = 0; n < 4; ++n)
                acc[m][n] = __builtin_amdgcn_mfma_f32_16x16x32_bf16(af[m], bfr[n], acc[m][n], 0, 0, 0);
        __syncthreads();
        cur = nxt;
    }
#pragma unroll
    for (int m = 0; m < 4; ++m) {
        int rb = m0 + wr + m * 16 + fq * 4;
#pragma unroll
        for (int n = 0; n < 4; ++n) {
            int col = n0 + wc + n * 16 + fr;
#pragma unroll
            for (int j = 0; j < 4; ++j) {
                int row = rb + j;
                if (row < T) oF[(long)row * 768 + col] = acc[m][n][j];
            }
        }
    }
}

// ---------------- GATv2 attention: single-pass online softmax, vectorized IO ----------------
__global__ __launch_bounds__(256) void k_att(
    const unsigned short* __restrict__ XLR,
    const int* __restrict__ off, const int* __restrict__ csr,
    const float* __restrict__ att, const float* __restrict__ bias,
    unsigned short* __restrict__ OUT) {
    const long sX = (long)MR * NLR;
    const long sO = (long)MR * KHC;
    int b = blockIdx.y;
    int i = blockIdx.x;
    const unsigned short* xl = XLR + (long)b * sX;
    const unsigned short* xr = xl + 1216;
    unsigned short* out = OUT + (long)b * sO;
    int lane = threadIdx.x & 63;
    int h = threadIdx.x >> 6;
    int c0 = lane * 4;
    int c1 = 256 + c0;
    bool tail = lane < 11;

    float xrf[8], attf[8];
    {
        const unsigned short* xp = xr + (long)i * NLR + h * C;
        ushort4 u0 = *(const ushort4*)(xp + c0);
        ushort4 u1 = tail ? *(const ushort4*)(xp + c1) : make_ushort4(0, 0, 0, 0);
        xrf[0] = b2f(u0.x); xrf[1] = b2f(u0.y); xrf[2] = b2f(u0.z); xrf[3] = b2f(u0.w);
        xrf[4] = b2f(u1.x); xrf[5] = b2f(u1.y); xrf[6] = b2f(u1.z); xrf[7] = b2f(u1.w);
        float4 a0 = *(const float4*)(att + h * C + c0);
        attf[0] = a0.x; attf[1] = a0.y; attf[2] = a0.z; attf[3] = a0.w;
        if (tail) {
            float4 a1 = *(const float4*)(att + h * C + c1);
            attf[4] = a1.x; attf[5] = a1.y; attf[6] = a1.z; attf[7] = a1.w;
        } else { attf[4] = attf[5] = attf[6] = attf[7] = 0.f; }
    }
    int o0 = off[b * (MAXM + 1) + i];
    int dg = off[b * (MAXM + 1) + i + 1] - o0;
    const int* cs = csr + b * E;

    float mx = -3e38f, den = 0.f;
    float acc[8] = {0.f, 0.f, 0.f, 0.f, 0.f, 0.f, 0.f, 0.f};
    auto step = [&](int s) {
        const unsigned short* xp = xl + (long)s * NLR + h * C;
        ushort4 v0 = *(const ushort4*)(xp + c0);
        ushort4 v1 = tail ? *(const ushort4*)(xp + c1) : make_ushort4(0, 0, 0, 0);
        float xv[8];
        xv[0] = b2f(v0.x); xv[1] = b2f(v0.y); xv[2] = b2f(v0.z); xv[3] = b2f(v0.w);
        xv[4] = b2f(v1.x); xv[5] = b2f(v1.y); xv[6] = b2f(v1.z); xv[7] = b2f(v1.w);
        float part = 0.f;
#pragma unroll
        for (int j = 0; j < 8; ++j) {
            float v = xv[j] + xrf[j];
            v = v > 0.f ? v : NEG * v;
            part += attf[j] * v;
        }
#pragma unroll
        for (int m = 1; m < 64; m <<= 1) part += __shfl_xor(part, m);
        float mn = fmaxf(mx, part);
        float sc = __expf(mx - mn);
        float p = __expf(part - mn);
        den = den * sc + p;
#pragma unroll
        for (int j = 0; j < 8; ++j) acc[j] = acc[j] * sc + p * xv[j];
        mx = mn;
    };
    step(i);
    for (int e = 0; e < dg; ++e) step(cs[o0 + e]);

    float inv = 1.f / den;
    unsigned short* op = out + (long)i * KHC + h * C;
    {
        float4 b0 = *(const float4*)(bias + h * C + c0);
        ushort4 s0;
        float v;
        v = acc[0] * inv + b0.x; s0.x = f2b(v > 0.f ? v : 0.f);
        v = acc[1] * inv + b0.y; s0.y = f2b(v > 0.f ? v : 0.f);
        v = acc[2] * inv + b0.z; s0.z = f2b(v > 0.f ? v : 0.f);
        v = acc[3] * inv + b0.w; s0.w = f2b(v > 0.f ? v : 0.f);
        *(ushort4*)(op + c0) = s0;
        if (tail) {
            float4 b1 = *(const float4*)(bias + h * C + c1);
            ushort4 s1;
            v = acc[4] * inv + b1.x; s1.x = f2b(v > 0.f ? v : 0.f);
            v = acc[5] * inv + b1.y; s1.y = f2b(v > 0.f ? v : 0.f);
            v = acc[6] * inv + b1.z; s1.z = f2b(v > 0.f ? v : 0.f);
            v = acc[7] * inv + b1.w; s1.w = f2b(v > 0.f ? v : 0.f);
            *(ushort4*)(op + c1) = s1;
        }
    }
    if (h == 0 && lane < KHC - HC)
        out[(long)i * KHC + HC + lane] = 0;
}

extern "C" void kernel_launch(void* const* d_in, const int* in_sizes, int n_in,
                              void* d_out, int out_size, void* d_ws, size_t ws_size,
                              hipStream_t stream) {
    const int*   kg    = (const int*)d_in[0];
    const float* emb   = (const float*)d_in[1];
    const float* Wl1   = (const float*)d_in[2];
    const float* bl1   = (const float*)d_in[3];
    const float* Wr1   = (const float*)d_in[4];
    const float* br1   = (const float*)d_in[5];
    const float* att1  = (const float*)d_in[6];
    const float* bias1 = (const float*)d_in[7];
    const float* Wl2   = (const float*)d_in[8];
    const float* bl2   = (const float*)d_in[9];
    const float* Wr2   = (const float*)d_in[10];
    const float* br2   = (const float*)d_in[11];
    const float* att2  = (const float*)d_in[12];
    const float* bias2 = (const float*)d_in[13];
    const float* Wp1   = (const float*)d_in[14];
    const float* bp1   = (const float*)d_in[15];
    const float* Wp2   = (const float*)d_in[16];
    const float* bp2   = (const float*)d_in[17];
    const float* Wlii  = (const float*)d_in[18];
    float* out = (float*)d_out;

    char* ws = (char*)d_ws;
    size_t o = 0;
    auto alloc = [&](size_t bytes) -> void* {
        void* p = ws + o;
        o = (o + bytes + 255) & ~(size_t)255;
        return p;
    };
    int* map  = (int*)alloc(sizeof(int) * B * V);
    int* list = (int*)alloc(sizeof(int) * B * MAXM);
    int* mcnt = (int*)alloc(sizeof(int) * B);
    int* off  = (int*)alloc(sizeof(int) * B * (MAXM + 1));
    int* csr  = (int*)alloc(sizeof(int) * B * E);
    int* tric = (int*)alloc(sizeof(int) * B * T * 3);

    long sXlr = (long)MR * NLR;
    long sHb  = (long)MR * KHC;
    long sEb  = (long)MR * KD;
    unsigned short* Xlr = (unsigned short*)alloc(2LL * B * sXlr);
    unsigned short* Hb  = (unsigned short*)alloc(2LL * B * sHb);
    unsigned short* Eb  = (unsigned short*)alloc(2LL * B * sEb);   // aliased as wb after L1 GEMM

    unsigned short* Wlr1t = (unsigned short*)alloc(2LL * 2432 * KD);
    unsigned short* Wlr2t = (unsigned short*)alloc(2LL * 2432 * KHC);
    unsigned short* Wp2t  = (unsigned short*)alloc(2LL * 384 * KD);
    unsigned short* Wp1b  = (unsigned short*)alloc(2LL * 1280 * 320);
    unsigned short* Wp12t = (unsigned short*)alloc(2LL * 384 * KHC);
    unsigned short* Wft2  = (unsigned short*)alloc(2LL * 768 * KF2);
    float* blr1 = (float*)alloc(sizeof(float) * NLR);
    float* blr2 = (float*)alloc(sizeof(float) * NLR);
    float* bp12 = (float*)alloc(sizeof(float) * 384);
    (void)ws_size; (void)in_sizes; (void)n_in; (void)out_size;

    unsigned short* wb = Eb;    // [B][MR][WB_LD=320] (Eb dead after layer-1 GEMM; KD==WB_LD)

    // graph
    k_init<<<(B * V + 255) / 256, 256, 0, stream>>>(map, list, mcnt);
    k_mark<<<(B * T * 3 + 255) / 256, 256, 0, stream>>>(kg, map);
    k_compact<<<dim3((V + 255) / 256, B), 256, 0, stream>>>(map, list, mcnt);
    k_graph<<<B, 256, 0, stream>>>(kg, map, off, csr, tric);

    // weight prep
    k_wt_all<<<4520, dim3(32, 8), 0, stream>>>(Wl1, Wr1, Wl2, Wr2, Wp1, Wp2, Wlii,
                                               bl1, br1, bl2, br2, bp1, bp2,
                                               Wlr1t, Wlr2t, Wp2t, Wp1b, Wft2,
                                               blr1, blr2, bp12);

    // embedding gather
    k_embgather<<<dim3(MAXM, B), 128, 0, stream>>>(emb, list, Eb);

    // Wp12t[n][k] = (Wp1 @ Wp2)[k][n]  (bf16 fused projection weight)
    k_mgemm<<<dim3(10, 3, 1), 256, 0, stream>>>(Wp2t, 0, KD, Wp1b, 320, nullptr,
                                                300, 1216, KD,
                                                nullptr, 0, 0, Wp12t, 0, KHC);

    long sWb = (long)MR * WB_LD;

    dim3 gL(19, 19, B);
    // layer 1 (combined Wl|Wr)
    k_mgemm<<<gL, 256, 0, stream>>>(Eb, sEb, KD, Wlr1t, KD, blr1, MAXM, NLR, KD,
                                    nullptr, 0, 0, Xlr, sXlr, NLR);
    k_att<<<dim3(MAXM, B), 256, 0, stream>>>(Xlr, off, csr, att1, bias1, Hb);
    // layer 2 (combined)
    k_mgemm<<<gL, 256, 0, stream>>>(Hb, sHb, KHC, Wlr2t, KHC, blr2, MAXM, NLR, KHC,
                                    nullptr, 0, 0, Xlr, sXlr, NLR);
    k_att<<<dim3(MAXM, B), 256, 0, stream>>>(Xlr, off, csr, att2, bias2, Hb);
    // fused projection: w = h @ Wp12 + bp12  (reads Hb, writes wb=Eb)
    k_mgemm<<<dim3(3, 19, B), 256, 0, stream>>>(Hb, sHb, KHC, Wp12t, KHC, bp12,
                                                MAXM, 300, KHC,
                                                nullptr, 0, 0, wb, sWb, WB_LD);
    // final (fused tric-gather)
    k_fgemm<<<dim3(6, 7, B), 256, 0, stream>>>(wb, sWb, tric, Wft2, out);
}

// Round 8
// 283.965 us; speedup vs baseline: 6.4735x; 1.1569x over previous
//
#include <hip/hip_runtime.h>
#include <hip/hip_bf16.h>

#define V 30000
#define D 300
#define H 4
#define C 300
#define HC 1200
#define B 2
#define T 800
#define E 1600          // real edges per sample
#define MAXM 2400       // max unique nodes per sample
#define NEG 0.2f
#define SCAN_CH ((MAXM + 255) / 256)

#define MR 2432         // node rows padded to 128-multiple (19*128)
#define KD 320          // D padded to 32-multiple
#define KHC 1216        // HC padded to 32-multiple
#define NLR 2432        // combined Wl|Wr output cols: [0,1200) xl, [1216,2416) xr
#define WB_LD 320       // w bf16 leading dim (300 -> 320 so 8-chunks never straddle parts)
#define KF2 960         // final K: 3 parts x 320

typedef __attribute__((ext_vector_type(8))) unsigned short u16x8;
typedef __attribute__((ext_vector_type(8))) short s16x8;
typedef __attribute__((ext_vector_type(4))) float f32x4;

__device__ inline unsigned short f2b(float v) {
    unsigned u = __float_as_uint(v);
    unsigned r = (u + 0x7FFFu + ((u >> 16) & 1u)) >> 16;
    return (unsigned short)r;
}
__device__ inline float b2f(unsigned short u) {
    return __uint_as_float(((unsigned)u) << 16);
}

// async global->LDS, 16B per lane (dest linear in tid per wave; SOURCE is per-lane)
#define GLOAD_LDS16(g, l) __builtin_amdgcn_global_load_lds( \
    (const __attribute__((address_space(1))) void*)(g), \
    (__attribute__((address_space(3))) void*)(l), 16, 0, 0)

// ---------------- graph build ----------------

__global__ void k_mark(const int* __restrict__ kg, int* map) {
    int i = blockIdx.x * blockDim.x + threadIdx.x;
    if (i >= B * T * 3) return;
    int b = i / (T * 3);
    map[b * V + kg[i]] = 1;
}

// ballot-aggregated compaction: one atomic per block (Guideline 12)
__global__ void k_compact(int* map, int* list, int* mcnt) {
    int b = blockIdx.y;
    int i = blockIdx.x * 256 + threadIdx.x;
    bool pred = (i < V) && (map[b * V + i] == 1);
    unsigned long long m = __ballot(pred);
    int lane = threadIdx.x & 63;
    int wid = threadIdx.x >> 6;
    __shared__ int wcnt[4];
    __shared__ int base;
    if (lane == 0) wcnt[wid] = __popcll(m);
    __syncthreads();
    if (threadIdx.x == 0) {
        int t = 0;
#pragma unroll
        for (int w2 = 0; w2 < 4; ++w2) { int c = wcnt[w2]; wcnt[w2] = t; t += c; }
        base = t ? atomicAdd(&mcnt[b], t) : 0;
    }
    __syncthreads();
    if (pred) {
        int idx = base + wcnt[wid] + __popcll(m & ((1ull << lane) - 1ull));
        map[b * V + i] = idx;
        list[b * MAXM + idx] = i;
    }
}

// edges + degree histogram + exclusive scan + CSR scatter, all in LDS, one block/sample
__global__ __launch_bounds__(256) void k_graph(const int* __restrict__ kg,
                                               const int* __restrict__ map,
                                               int* __restrict__ off_g,
                                               int* __restrict__ csr,
                                               int* __restrict__ tric) {
    int b = blockIdx.x;
    int tid = threadIdx.x;
    __shared__ int sdeg[MAXM];
    __shared__ int soff[MAXM + 1];
    __shared__ int ses[E];
    __shared__ int sed[E];
    __shared__ int ts[256];
    for (int j = tid; j < MAXM; j += 256) sdeg[j] = 0;
    __syncthreads();
    for (int t = tid; t < T; t += 256) {
        const int* kk = kg + ((long)b * T + t) * 3;
        int hc = map[b * V + kk[0]];
        int rc = map[b * V + kk[1]];
        int tc = map[b * V + kk[2]];
        ses[t] = hc;     sed[t] = rc;
        ses[T + t] = rc; sed[T + t] = tc;
        atomicAdd(&sdeg[rc], 1);
        atomicAdd(&sdeg[tc], 1);
        int* tr = tric + ((long)b * T + t) * 3;
        tr[0] = hc; tr[1] = rc; tr[2] = tc;
    }
    __syncthreads();
    // exclusive scan sdeg -> soff
    int base = tid * SCAN_CH;
    int loc[SCAN_CH];
    int sum = 0;
#pragma unroll
    for (int j = 0; j < SCAN_CH; ++j) {
        int v = (base + j < MAXM) ? sdeg[base + j] : 0;
        sum += v; loc[j] = sum;
    }
    ts[tid] = sum; __syncthreads();
    for (int s = 1; s < 256; s <<= 1) {
        int v = (tid >= s) ? ts[tid - s] : 0;
        __syncthreads();
        ts[tid] += v;
        __syncthreads();
    }
    int excl = (tid > 0) ? ts[tid - 1] : 0;
#pragma unroll
    for (int j = 0; j < SCAN_CH; ++j)
        if (base + j < MAXM) soff[base + j + 1] = excl + loc[j];
    if (tid == 0) soff[0] = 0;
    __syncthreads();
    // reuse sdeg as fill counters
    for (int j = tid; j < MAXM; j += 256) sdeg[j] = 0;
    __syncthreads();
    for (int e = tid; e < E; e += 256) {
        int d = sed[e];
        int pos = soff[d] + atomicAdd(&sdeg[d], 1);
        csr[b * E + pos] = ses[e];
    }
    for (int j = tid; j <= MAXM; j += 256) off_g[b * (MAXM + 1) + j] = soff[j];
}

// ---------------- fused weight prep ----------------
__global__ void k_wt_all(const float* __restrict__ Wl1, const float* __restrict__ Wr1,
                         const float* __restrict__ Wl2, const float* __restrict__ Wr2,
                         const float* __restrict__ Wp1, const float* __restrict__ Wp2,
                         const float* __restrict__ Wlii,
                         const float* __restrict__ bl1, const float* __restrict__ br1,
                         const float* __restrict__ bl2, const float* __restrict__ br2,
                         const float* __restrict__ bp1, const float* __restrict__ bp2,
                         unsigned short* Wlr1t, unsigned short* Wlr2t,
                         unsigned short* Wp2t, unsigned short* Wp1b,
                         unsigned short* Wft2,
                         float* blr1, float* blr2, float* bp12) {
    const int KT[6]  = {10, 10, 38, 38, 10, 30};
    const int CUM[10] = {0, 380, 760, 2204, 3648, 3748, 4468, 4508, 4518, 4520};
    int bid = blockIdx.x;
    int task = 0;
    while (bid >= CUM[task + 1]) ++task;
    int local = bid - CUM[task];
    int tx = threadIdx.x, ty = threadIdx.y;
    int tid = ty * 32 + tx;

    if (task == 6) {   // Wp1b copy: bf16 [1280][320] row-major, zero-padded
        int r0 = local * 32;
#pragma unroll
        for (int p = 0; p < 4; ++p) {
            int row = r0 + ty + p * 8;
#pragma unroll
            for (int j = 0; j < 10; ++j) {
                int c = tx + j * 32;
                unsigned short v = 0;
                if (row < 1200 && c < 300) v = f2b(Wp1[(long)row * 300 + c]);
                Wp1b[(long)row * 320 + c] = v;
            }
        }
        return;
    }
    if (task == 7) {   // combined biases
        int c = local * 256 + tid;
        if (c < NLR) {
            float v1 = 0.f, v2 = 0.f;
            if (c < 1200) { v1 = bl1[c]; v2 = bl2[c]; }
            else if (c >= 1216 && c < 2416) { v1 = br1[c - 1216]; v2 = br2[c - 1216]; }
            blr1[c] = v1; blr2[c] = v2;
        }
        return;
    }
    if (task == 8) {   // bp12 = bp1 @ Wp2 + bp2
        int n = local * 256 + tid;
        if (n < 300) {
            float s = bp2[n];
            for (int m = 0; m < 300; ++m) s += bp1[m] * Wp2[(long)m * 300 + n];
            bp12[n] = s;
        }
        return;
    }

    __shared__ float t[32][33];
    if (task == 5) {   // Wlii -> Wft2[768][960] (part-320 k layout)
        int kt = local % 30, nt = local / 30;
        int k0 = kt * 32, n0 = nt * 32;
#pragma unroll
        for (int p = 0; p < 4; ++p) {
            int gk = k0 + ty + p * 8, n = n0 + tx;
            int pp = (gk >= 640) ? 2 : (gk >= 320 ? 1 : 0);
            int kc = gk - pp * 320;
            t[ty + p * 8][tx] = (kc < 300) ? Wlii[(long)(300 * pp + kc) * 768 + n] : 0.f;
        }
        __syncthreads();
#pragma unroll
        for (int p = 0; p < 4; ++p) {
            int n = n0 + ty + p * 8, gk = k0 + tx;
            Wft2[(long)n * 960 + gk] = f2b(t[tx][ty + p * 8]);
        }
        return;
    }

    int kt = local % KT[task], nt = local / KT[task];
    const float* W; unsigned short* Wt; int K, N, Kp;
    switch (task) {
        case 0: W = Wl1;  Wt = Wlr1t;                     K = 300;  N = 1200; Kp = KD;  break;
        case 1: W = Wr1;  Wt = Wlr1t + (long)1216 * KD;   K = 300;  N = 1200; Kp = KD;  break;
        case 2: W = Wl2;  Wt = Wlr2t;                     K = 1200; N = 1200; Kp = KHC; break;
        case 3: W = Wr2;  Wt = Wlr2t + (long)1216 * KHC;  K = 1200; N = 1200; Kp = KHC; break;
        default: W = Wp2; Wt = Wp2t;                      K = 300;  N = 300;  Kp = KD;  break;
    }
    int k0 = kt * 32, n0 = nt * 32;
#pragma unroll
    for (int p = 0; p < 4; ++p) {
        int k = k0 + ty + p * 8, n = n0 + tx;
        t[ty + p * 8][tx] = (k < K && n < N) ? W[(long)k * N + n] : 0.f;
    }
    __syncthreads();
#pragma unroll
    for (int p = 0; p < 4; ++p) {
        int n = n0 + ty + p * 8, k = k0 + tx;
        Wt[(long)n * Kp + k] = f2b(t[tx][ty + p * 8]);
    }
}

// ---------------- embedding gather f32 -> bf16 padded (vectorized, G13) ----------------
__global__ void k_embgather(const float* __restrict__ emb, const int* __restrict__ list,
                            unsigned short* __restrict__ Eb) {
    int b = blockIdx.y, i = blockIdx.x;
    int src = list[b * MAXM + i];
    const float* e = emb + (long)src * D;
    unsigned short* o = Eb + ((long)b * MR + i) * KD;
    int c = threadIdx.x;
    if (c < 75) {
        float4 v = *(const float4*)(e + c * 4);
        ushort4 u;
        u.x = f2b(v.x); u.y = f2b(v.y); u.z = f2b(v.z); u.w = f2b(v.w);
        *(ushort4*)(o + c * 4) = u;
    } else if (c < 80) {
        *(ushort4*)(o + c * 4) = make_ushort4(0, 0, 0, 0);
    }
}

// ---------------- block-swizzle decode (bijective XCD chunking + group-M) ----------------
__device__ inline void tile_decode(int& m0, int& n0) {
    int nbx = gridDim.x, nby = gridDim.y;
    int nwg = nbx * nby;
    int wg = blockIdx.y * nbx + blockIdx.x;
    int q = nwg >> 3, r8 = nwg & 7;
    int xcd = wg & 7, idx = wg >> 3;
    int L = (xcd < r8 ? xcd * (q + 1) : r8 * (q + 1) + (xcd - r8) * q) + idx;
    const int G = 4;
    int band = L / (G * nbx);
    int first = band * G;
    int sz = min(G, nby - first);
    int rem = L - band * G * nbx;
    int by = first + rem % sz;
    int bx = rem / sz;
    m0 = by * 128; n0 = bx * 128;
}

// ---------------- bf16 MFMA GEMM: depth-2 counted-vmcnt pipeline (T3+T4) --------
// LDS: 3 staging buf pairs (48KB); C-tile overlays [0,32KB) in epilogue.
__global__ __launch_bounds__(256) void k_mgemm(
    const unsigned short* __restrict__ A, long sA, int lda,
    const unsigned short* __restrict__ Wt, int ldw,
    const float* __restrict__ bias,
    int N, int K,
    unsigned short* __restrict__ outB, long sB, int ldb_) {
    int b = blockIdx.z;
    A += (long)b * sA;
    __shared__ unsigned short lds[3 * 8192];   // ushorts: A bufs @ buf*4096, B bufs @ 12288+buf*4096
    int tid = threadIdx.x;
    int m0, n0; tile_decode(m0, n0);

    int w = tid >> 6, lane = tid & 63;
    int wr = (w >> 1) * 64, wc = (w & 1) * 64;
    int fr = lane & 15, fq = lane >> 4;
    int r0 = tid >> 2, sg = tid & 3;
    int swz = (sg ^ ((r0 >> 1) & 3)) * 8;   // pre-swizzled global chunk (involution)
    const unsigned short* Ap  = A  + (long)(m0 + r0) * lda + swz;
    const unsigned short* Ap2 = A  + (long)(m0 + r0 + 64) * lda + swz;
    const unsigned short* Bp  = Wt + (long)(n0 + r0) * ldw + swz;
    const unsigned short* Bp2 = Wt + (long)(n0 + r0 + 64) * ldw + swz;

    auto stage = [&](int buf, int k0) {
        unsigned short* a_ = lds + buf * 4096;
        unsigned short* b_ = lds + 12288 + buf * 4096;
        GLOAD_LDS16(Ap + k0,  a_ + r0 * 32 + sg * 8);
        GLOAD_LDS16(Ap2 + k0, a_ + (r0 + 64) * 32 + sg * 8);
        GLOAD_LDS16(Bp + k0,  b_ + r0 * 32 + sg * 8);
        GLOAD_LDS16(Bp2 + k0, b_ + (r0 + 64) * 32 + sg * 8);
    };

    f32x4 acc[4][4] = {};
    int NT = K >> 5;
    stage(0, 0);
    stage(1, 32);          // all K here have NT >= 10
    int cur = 0, stg = 2;
    for (int i = 0; i < NT; ++i) {
        if (i + 1 < NT) asm volatile("s_waitcnt vmcnt(4)" ::: "memory");
        else            asm volatile("s_waitcnt vmcnt(0)" ::: "memory");
        __builtin_amdgcn_s_barrier();
        __builtin_amdgcn_sched_barrier(0);
        if (i + 2 < NT) stage(stg, (i + 2) << 5);
        const unsigned short* a_ = lds + cur * 4096;
        const unsigned short* b_ = lds + 12288 + cur * 4096;
        s16x8 af[4], bfr[4];
#pragma unroll
        for (int m = 0; m < 4; ++m) {
            int rr = wr + m * 16 + fr;
            af[m] = *(const s16x8*)&a_[rr * 32 + (fq ^ ((rr >> 1) & 3)) * 8];
        }
#pragma unroll
        for (int n = 0; n < 4; ++n) {
            int rr = wc + n * 16 + fr;
            bfr[n] = *(const s16x8*)&b_[rr * 32 + (fq ^ ((rr >> 1) & 3)) * 8];
        }
#pragma unroll
        for (int m = 0; m < 4; ++m)
#pragma unroll
            for (int n = 0; n < 4; ++n)
                acc[m][n] = __builtin_amdgcn_mfma_f32_16x16x32_bf16(af[m], bfr[n], acc[m][n], 0, 0, 0);
        cur = (cur == 2) ? 0 : cur + 1;
        stg = (stg == 2) ? 0 : stg + 1;
    }
    // ---- epilogue: stage C-tile in LDS (overlay), store coalesced ushort8 rows ----
    __syncthreads();
#pragma unroll
    for (int m = 0; m < 4; ++m) {
        int rl = wr + m * 16 + fq * 4;
#pragma unroll
        for (int n = 0; n < 4; ++n) {
            int cl = wc + n * 16 + fr;
            int colg = n0 + cl;
            float bi = (colg < N && bias) ? bias[colg] : 0.f;
#pragma unroll
            for (int j = 0; j < 4; ++j) {
                unsigned short v = (colg < N) ? f2b(acc[m][n][j] + bi) : (unsigned short)0;
                lds[(rl + j) * 128 + cl] = v;
            }
        }
    }
    __syncthreads();
    unsigned short* oB = outB + (long)b * sB;
#pragma unroll
    for (int q = 0; q < 8; ++q) {
        int idx = q * 256 + tid;
        int row = idx >> 4, c8 = idx & 15;
        int colg = n0 + c8 * 8;
        if (colg < ldb_)
            *(u16x8*)(oB + (long)(m0 + row) * ldb_ + colg) = *(const u16x8*)&lds[row * 128 + c8 * 8];
    }
}

// ---------------- final GEMM with fused tric-gather A (depth-2 pipeline) ----------------
__global__ __launch_bounds__(256) void k_fgemm(
    const unsigned short* __restrict__ wb, long sW,
    const int* __restrict__ tric,
    const unsigned short* __restrict__ Wft2,
    float* __restrict__ out) {
    int b = blockIdx.z;
    const unsigned short* wB = wb + (long)b * sW;
    const int* tr = tric + (long)b * T * 3;
    float* oF = out + (long)b * T * 768;
    __shared__ unsigned short lds[3 * 8192];
    int tid = threadIdx.x;
    int m0, n0; tile_decode(m0, n0);

    int w = tid >> 6, lane = tid & 63;
    int wr = (w >> 1) * 64, wc = (w & 1) * 64;
    int fr = lane & 15, fq = lane >> 4;
    int r0 = tid >> 2, sg = tid & 3;
    int swz = (sg ^ ((r0 >> 1) & 3)) * 8;

    int gm  = m0 + r0;
    int gm2 = gm + 64;
    int t1 = min(gm, T - 1) * 3, t2 = min(gm2, T - 1) * 3;
    int tr_a[3] = {tr[t1], tr[t1 + 1], tr[t1 + 2]};
    int tr_b[3] = {tr[t2], tr[t2 + 1], tr[t2 + 2]};

    const unsigned short* Bp  = Wft2 + (long)(n0 + r0) * KF2 + swz;
    const unsigned short* Bp2 = Wft2 + (long)(n0 + r0 + 64) * KF2 + swz;

    auto stage = [&](int buf, int k0) {
        unsigned short* a_ = lds + buf * 4096;
        unsigned short* b_ = lds + 12288 + buf * 4096;
        int kk = k0 + swz;
        int p_ = (kk >= 640) ? 2 : (kk >= 320 ? 1 : 0);
        int kc = kk - p_ * 320;
        GLOAD_LDS16(wB + (long)tr_a[p_] * WB_LD + kc, a_ + r0 * 32 + sg * 8);
        GLOAD_LDS16(wB + (long)tr_b[p_] * WB_LD + kc, a_ + (r0 + 64) * 32 + sg * 8);
        GLOAD_LDS16(Bp + k0,  b_ + r0 * 32 + sg * 8);
        GLOAD_LDS16(Bp2 + k0, b_ + (r0 + 64) * 32 + sg * 8);
    };

    f32x4 acc[4][4] = {};
    const int NT = KF2 >> 5;   // 30
    stage(0, 0);
    stage(1, 32);
    int cur = 0, stg = 2;
    for (int i = 0; i < NT; ++i) {
        if (i + 1 < NT) asm volatile("s_waitcnt vmcnt(4)" ::: "memory");
        else            asm volatile("s_waitcnt vmcnt(0)" ::: "memory");
        __builtin_amdgcn_s_barrier();
        __builtin_amdgcn_sched_barrier(0);
        if (i + 2 < NT) stage(stg, (i + 2) << 5);
        const unsigned short* a_ = lds + cur * 4096;
        const unsigned short* b_ = lds + 12288 + cur * 4096;
        s16x8 af[4], bfr[4];
#pragma unroll
        for (int m = 0; m < 4; ++m) {
            int rr = wr + m * 16 + fr;
            af[m] = *(const s16x8*)&a_[rr * 32 + (fq ^ ((rr >> 1) & 3)) * 8];
        }
#pragma unroll
        for (int n = 0; n < 4; ++n) {
            int rr = wc + n * 16 + fr;
            bfr[n] = *(const s16x8*)&b_[rr * 32 + (fq ^ ((rr >> 1) & 3)) * 8];
        }
#pragma unroll
        for (int m = 0; m < 4; ++m)
#pragma unroll
            for (int n = 0; n < 4; ++n)
                acc[m][n] = __builtin_amdgcn_mfma_f32_16x16x32_bf16(af[m], bfr[n], acc[m][n], 0, 0, 0);
        cur = (cur == 2) ? 0 : cur + 1;
        stg = (stg == 2) ? 0 : stg + 1;
    }
#pragma unroll
    for (int m = 0; m < 4; ++m) {
        int rb = m0 + wr + m * 16 + fq * 4;
#pragma unroll
        for (int n = 0; n < 4; ++n) {
            int col = n0 + wc + n * 16 + fr;
#pragma unroll
            for (int j = 0; j < 4; ++j) {
                int row = rb + j;
                if (row < T) oF[(long)row * 768 + col] = acc[m][n][j];
            }
        }
    }
}

// ---------------- GATv2 attention: single-pass online softmax, vectorized IO ----------------
__global__ __launch_bounds__(256) void k_att(
    const unsigned short* __restrict__ XLR,
    const int* __restrict__ off, const int* __restrict__ csr,
    const float* __restrict__ att, const float* __restrict__ bias,
    unsigned short* __restrict__ OUT) {
    const long sX = (long)MR * NLR;
    const long sO = (long)MR * KHC;
    int b = blockIdx.y;
    int i = blockIdx.x;
    const unsigned short* xl = XLR + (long)b * sX;
    const unsigned short* xr = xl + 1216;
    unsigned short* out = OUT + (long)b * sO;
    int lane = threadIdx.x & 63;
    int h = threadIdx.x >> 6;
    int c0 = lane * 4;
    int c1 = 256 + c0;
    bool tail = lane < 11;

    float xrf[8], attf[8];
    {
        const unsigned short* xp = xr + (long)i * NLR + h * C;
        ushort4 u0 = *(const ushort4*)(xp + c0);
        ushort4 u1 = tail ? *(const ushort4*)(xp + c1) : make_ushort4(0, 0, 0, 0);
        xrf[0] = b2f(u0.x); xrf[1] = b2f(u0.y); xrf[2] = b2f(u0.z); xrf[3] = b2f(u0.w);
        xrf[4] = b2f(u1.x); xrf[5] = b2f(u1.y); xrf[6] = b2f(u1.z); xrf[7] = b2f(u1.w);
        float4 a0 = *(const float4*)(att + h * C + c0);
        attf[0] = a0.x; attf[1] = a0.y; attf[2] = a0.z; attf[3] = a0.w;
        if (tail) {
            float4 a1 = *(const float4*)(att + h * C + c1);
            attf[4] = a1.x; attf[5] = a1.y; attf[6] = a1.z; attf[7] = a1.w;
        } else { attf[4] = attf[5] = attf[6] = attf[7] = 0.f; }
    }
    int o0 = off[b * (MAXM + 1) + i];
    int dg = off[b * (MAXM + 1) + i + 1] - o0;
    const int* cs = csr + b * E;

    float mx = -3e38f, den = 0.f;
    float acc[8] = {0.f, 0.f, 0.f, 0.f, 0.f, 0.f, 0.f, 0.f};
    auto step = [&](int s) {
        const unsigned short* xp = xl + (long)s * NLR + h * C;
        ushort4 v0 = *(const ushort4*)(xp + c0);
        ushort4 v1 = tail ? *(const ushort4*)(xp + c1) : make_ushort4(0, 0, 0, 0);
        float xv[8];
        xv[0] = b2f(v0.x); xv[1] = b2f(v0.y); xv[2] = b2f(v0.z); xv[3] = b2f(v0.w);
        xv[4] = b2f(v1.x); xv[5] = b2f(v1.y); xv[6] = b2f(v1.z); xv[7] = b2f(v1.w);
        float part = 0.f;
#pragma unroll
        for (int j = 0; j < 8; ++j) {
            float v = xv[j] + xrf[j];
            v = v > 0.f ? v : NEG * v;
            part += attf[j] * v;
        }
#pragma unroll
        for (int m = 1; m < 64; m <<= 1) part += __shfl_xor(part, m);
        float mn = fmaxf(mx, part);
        float sc = __expf(mx - mn);
        float p = __expf(part - mn);
        den = den * sc + p;
#pragma unroll
        for (int j = 0; j < 8; ++j) acc[j] = acc[j] * sc + p * xv[j];
        mx = mn;
    };
    step(i);
    for (int e = 0; e < dg; ++e) step(cs[o0 + e]);

    float inv = 1.f / den;
    unsigned short* op = out + (long)i * KHC + h * C;
    {
        float4 b0 = *(const float4*)(bias + h * C + c0);
        ushort4 s0;
        float v;
        v = acc[0] * inv + b0.x; s0.x = f2b(v > 0.f ? v : 0.f);
        v = acc[1] * inv + b0.y; s0.y = f2b(v > 0.f ? v : 0.f);
        v = acc[2] * inv + b0.z; s0.z = f2b(v > 0.f ? v : 0.f);
        v = acc[3] * inv + b0.w; s0.w = f2b(v > 0.f ? v : 0.f);
        *(ushort4*)(op + c0) = s0;
        if (tail) {
            float4 b1 = *(const float4*)(bias + h * C + c1);
            ushort4 s1;
            v = acc[4] * inv + b1.x; s1.x = f2b(v > 0.f ? v : 0.f);
            v = acc[5] * inv + b1.y; s1.y = f2b(v > 0.f ? v : 0.f);
            v = acc[6] * inv + b1.z; s1.z = f2b(v > 0.f ? v : 0.f);
            v = acc[7] * inv + b1.w; s1.w = f2b(v > 0.f ? v : 0.f);
            *(ushort4*)(op + c1) = s1;
        }
    }
    if (h == 0 && lane < KHC - HC)
        out[(long)i * KHC + HC + lane] = 0;
}

extern "C" void kernel_launch(void* const* d_in, const int* in_sizes, int n_in,
                              void* d_out, int out_size, void* d_ws, size_t ws_size,
                              hipStream_t stream) {
    const int*   kg    = (const int*)d_in[0];
    const float* emb   = (const float*)d_in[1];
    const float* Wl1   = (const float*)d_in[2];
    const float* bl1   = (const float*)d_in[3];
    const float* Wr1   = (const float*)d_in[4];
    const float* br1   = (const float*)d_in[5];
    const float* att1  = (const float*)d_in[6];
    const float* bias1 = (const float*)d_in[7];
    const float* Wl2   = (const float*)d_in[8];
    const float* bl2   = (const float*)d_in[9];
    const float* Wr2   = (const float*)d_in[10];
    const float* br2   = (const float*)d_in[11];
    const float* att2  = (const float*)d_in[12];
    const float* bias2 = (const float*)d_in[13];
    const float* Wp1   = (const float*)d_in[14];
    const float* bp1   = (const float*)d_in[15];
    const float* Wp2   = (const float*)d_in[16];
    const float* bp2   = (const float*)d_in[17];
    const float* Wlii  = (const float*)d_in[18];
    float* out = (float*)d_out;

    char* ws = (char*)d_ws;
    size_t o = 0;
    auto alloc = [&](size_t bytes) -> void* {
        void* p = ws + o;
        o = (o + bytes + 255) & ~(size_t)255;
        return p;
    };
    int* map  = (int*)alloc(sizeof(int) * B * V);
    int* list = (int*)alloc(sizeof(int) * B * MAXM);
    int* mcnt = (int*)alloc(sizeof(int) * B);
    int* off  = (int*)alloc(sizeof(int) * B * (MAXM + 1));
    int* csr  = (int*)alloc(sizeof(int) * B * E);
    int* tric = (int*)alloc(sizeof(int) * B * T * 3);

    long sXlr = (long)MR * NLR;
    long sHb  = (long)MR * KHC;
    long sEb  = (long)MR * KD;
    unsigned short* Xlr = (unsigned short*)alloc(2LL * B * sXlr);
    unsigned short* Hb  = (unsigned short*)alloc(2LL * B * sHb);
    unsigned short* Eb  = (unsigned short*)alloc(2LL * B * sEb);   // aliased as wb after L1 GEMM

    unsigned short* Wlr1t = (unsigned short*)alloc(2LL * 2432 * KD);
    unsigned short* Wlr2t = (unsigned short*)alloc(2LL * 2432 * KHC);
    unsigned short* Wp2t  = (unsigned short*)alloc(2LL * 384 * KD);
    unsigned short* Wp1b  = (unsigned short*)alloc(2LL * 1280 * 320);
    unsigned short* Wp12t = (unsigned short*)alloc(2LL * 384 * KHC);
    unsigned short* Wft2  = (unsigned short*)alloc(2LL * 768 * KF2);
    float* blr1 = (float*)alloc(sizeof(float) * NLR);
    float* blr2 = (float*)alloc(sizeof(float) * NLR);
    float* bp12 = (float*)alloc(sizeof(float) * 384);
    (void)ws_size; (void)in_sizes; (void)n_in; (void)out_size;

    unsigned short* wb = Eb;    // [B][MR][WB_LD=320] (Eb dead after layer-1 GEMM; KD==WB_LD)

    // graph: init via async memsets (map = -1, list = 0, mcnt = 0)
    hipMemsetAsync(map, 0xFF, sizeof(int) * B * V, stream);
    hipMemsetAsync(list, 0, sizeof(int) * B * MAXM, stream);
    hipMemsetAsync(mcnt, 0, sizeof(int) * B, stream);
    k_mark<<<(B * T * 3 + 255) / 256, 256, 0, stream>>>(kg, map);
    k_compact<<<dim3((V + 255) / 256, B), 256, 0, stream>>>(map, list, mcnt);
    k_graph<<<B, 256, 0, stream>>>(kg, map, off, csr, tric);

    // weight prep
    k_wt_all<<<4520, dim3(32, 8), 0, stream>>>(Wl1, Wr1, Wl2, Wr2, Wp1, Wp2, Wlii,
                                               bl1, br1, bl2, br2, bp1, bp2,
                                               Wlr1t, Wlr2t, Wp2t, Wp1b, Wft2,
                                               blr1, blr2, bp12);

    // embedding gather
    k_embgather<<<dim3(MAXM, B), 128, 0, stream>>>(emb, list, Eb);

    // Wp12t[n][k] = (Wp1 @ Wp2)[k][n]  (bf16 fused projection weight)
    k_mgemm<<<dim3(10, 3, 1), 256, 0, stream>>>(Wp2t, 0, KD, Wp1b, 320, nullptr,
                                                1216, KD, Wp12t, 0, KHC);

    long sWb = (long)MR * WB_LD;

    dim3 gL(19, 19, B);
    // layer 1 (combined Wl|Wr)
    k_mgemm<<<gL, 256, 0, stream>>>(Eb, sEb, KD, Wlr1t, KD, blr1,
                                    NLR, KD, Xlr, sXlr, NLR);
    k_att<<<dim3(MAXM, B), 256, 0, stream>>>(Xlr, off, csr, att1, bias1, Hb);
    // layer 2 (combined)
    k_mgemm<<<gL, 256, 0, stream>>>(Hb, sHb, KHC, Wlr2t, KHC, blr2,
                                    NLR, KHC, Xlr, sXlr, NLR);
    k_att<<<dim3(MAXM, B), 256, 0, stream>>>(Xlr, off, csr, att2, bias2, Hb);
    // fused projection: w = h @ Wp12 + bp12  (reads Hb, writes wb=Eb)
    k_mgemm<<<dim3(3, 19, B), 256, 0, stream>>>(Hb, sHb, KHC, Wp12t, KHC, bp12,
                                                300, KHC, wb, sWb, WB_LD);
    // final (fused tric-gather)
    k_fgemm<<<dim3(6, 7, B), 256, 0, stream>>>(wb, sWb, tric, Wft2, out);
}